// Round 1
// baseline (9311.373 us; speedup 1.0000x reference)
//
#include <hip/hip_runtime.h>
#include <math.h>

#define NB 8
#define C2 512
#define C3 1024
#define HIN2 28
#define HIN3 14
#define HO2 27
#define HO3 13
#define CC 1536
#define NP (NB*HO2*HO2)   /* 5832 */
#define NM 32000
#define NKNN 9
#define OH 224
#define AMAP_N (NB*OH*OH) /* 401408 */

typedef unsigned long long u64;
typedef unsigned int u32;

struct GW { float w[33]; };

__device__ __forceinline__ float warp_sum(float v){
  #pragma unroll
  for (int off=32; off; off>>=1) v += __shfl_down(v, off);
  return v;
}

// ---------------- avg pool k=4,s=1,p=1 (count_include_pad -> /16) ----------------
__global__ void k_avgpool2(const float* __restrict__ in, float* __restrict__ emb){
  int t = blockIdx.x*256 + threadIdx.x;
  if (t >= NB*HO2*HO2*C2) return;
  int c = t % C2; int r = t / C2;
  int j = r % HO2; r /= HO2;
  int i = r % HO2; int b = r / HO2;
  const float* plane = in + ((size_t)(b*C2 + c)*HIN2)*HIN2;
  float s = 0.f;
  #pragma unroll
  for (int di=0; di<4; ++di){
    int y = i - 1 + di;
    if ((unsigned)y >= HIN2) continue;
    #pragma unroll
    for (int dj=0; dj<4; ++dj){
      int x = j - 1 + dj;
      if ((unsigned)x < HIN2) s += plane[y*HIN2 + x];
    }
  }
  emb[((size_t)((b*HO2 + i)*HO2 + j))*CC + c] = s * (1.f/16.f);
}

__global__ void k_avgpool3(const float* __restrict__ in, float* __restrict__ f3p){
  int t = blockIdx.x*256 + threadIdx.x;
  if (t >= NB*HO3*HO3*C3) return;
  int c = t % C3; int r = t / C3;
  int j = r % HO3; r /= HO3;
  int i = r % HO3; int b = r / HO3;
  const float* plane = in + ((size_t)(b*C3 + c)*HIN3)*HIN3;
  float s = 0.f;
  #pragma unroll
  for (int di=0; di<4; ++di){
    int y = i - 1 + di;
    if ((unsigned)y >= HIN3) continue;
    #pragma unroll
    for (int dj=0; dj<4; ++dj){
      int x = j - 1 + dj;
      if ((unsigned)x < HIN3) s += plane[y*HIN3 + x];
    }
  }
  f3p[((size_t)((b*HO3 + i)*HO3 + j))*C3 + c] = s * (1.f/16.f);
}

// ---------------- bilinear 13x13 -> 27x27 (half-pixel, clamp taps) ----------------
__global__ void k_upsample3(const float* __restrict__ f3p, float* __restrict__ emb){
  int t = blockIdx.x*256 + threadIdx.x;
  if (t >= NB*HO2*HO2*C3) return;
  int c = t % C3; int r = t / C3;
  int ox = r % HO2; r /= HO2;
  int oy = r % HO2; int b = r / HO2;
  float fy = (oy + 0.5f) * (13.f/27.f) - 0.5f;
  float fx = (ox + 0.5f) * (13.f/27.f) - 0.5f;
  int y0 = (int)floorf(fy); float wy = fy - (float)y0;
  int x0 = (int)floorf(fx); float wx = fx - (float)x0;
  int y0c = min(max(y0,0), HO3-1), y1c = min(max(y0+1,0), HO3-1);
  int x0c = min(max(x0,0), HO3-1), x1c = min(max(x0+1,0), HO3-1);
  const float* base = f3p + (size_t)(b*HO3*HO3)*C3;
  float v00 = base[(size_t)(y0c*HO3 + x0c)*C3 + c];
  float v01 = base[(size_t)(y0c*HO3 + x1c)*C3 + c];
  float v10 = base[(size_t)(y1c*HO3 + x0c)*C3 + c];
  float v11 = base[(size_t)(y1c*HO3 + x1c)*C3 + c];
  float v = (1.f-wy)*((1.f-wx)*v00 + wx*v01) + wy*((1.f-wx)*v10 + wx*v11);
  emb[((size_t)((b*HO2 + oy)*HO2 + ox))*CC + C2 + c] = v;
}

// ---------------- row sum of squares ----------------
__global__ void k_rowsumsq(const float* __restrict__ src, float* __restrict__ dst, int rows){
  int wave = threadIdx.x >> 6;
  int lane = threadIdx.x & 63;
  int r = blockIdx.x*4 + wave;
  if (r >= rows) return;
  const float4* p = (const float4*)(src + (size_t)r*CC);
  float s = 0.f;
  #pragma unroll
  for (int it=0; it<6; ++it){
    float4 v = p[it*64 + lane];
    s += v.x*v.x + v.y*v.y + v.z*v.z + v.w*v.w;
  }
  s = warp_sum(s);
  if (lane==0) dst[r] = s;
}

__global__ void k_init(u64* __restrict__ packed){
  int t = blockIdx.x*256 + threadIdx.x;
  if (t < NP) packed[t] = ~0ull;
}

// ---------------- fused distance + min/argmin GEMM ----------------
#define TM 64
#define TN 64
#define TKc 32
#define NTILE 10

__global__ __launch_bounds__(256) void k_distmin(const float* __restrict__ emb,
    const float* __restrict__ bank, const float* __restrict__ x2,
    const float* __restrict__ y2, u64* __restrict__ packed){
  __shared__ float As[TKc][TM];
  __shared__ float Bs[TKc][TN];
  int tid = threadIdx.x;
  int ty = tid >> 4, tx = tid & 15;
  int m0 = blockIdx.x * TM;
  int srow = tid >> 2;          // 0..63
  int skk  = (tid & 3) * 8;     // 0,8,16,24
  int arow = min(m0 + srow, NP-1);
  const float* aptr = emb + (size_t)arow*CC + skk;
  float px2[4];
  #pragma unroll
  for (int i=0;i<4;i++){
    int pr = m0 + ty*4 + i;
    px2[i] = x2[min(pr, NP-1)];
  }
  float bestVal[4]; int bestIdx[4];
  #pragma unroll
  for (int i=0;i<4;i++){ bestVal[i]=3.4e38f; bestIdx[i]=0; }

  for (int bt = 0; bt < NTILE; ++bt){
    int n0 = (blockIdx.y * NTILE + bt) * TN;
    const float* bptr = bank + (size_t)(n0 + srow)*CC + skk;
    float acc[4][4];
    #pragma unroll
    for (int i=0;i<4;i++)
      #pragma unroll
      for (int j=0;j<4;j++) acc[i][j]=0.f;

    for (int k0 = 0; k0 < CC; k0 += TKc){
      float4 a0 = *(const float4*)(aptr + k0);
      float4 a1 = *(const float4*)(aptr + k0 + 4);
      float4 b0 = *(const float4*)(bptr + k0);
      float4 b1 = *(const float4*)(bptr + k0 + 4);
      __syncthreads();
      As[skk+0][srow]=a0.x; As[skk+1][srow]=a0.y; As[skk+2][srow]=a0.z; As[skk+3][srow]=a0.w;
      As[skk+4][srow]=a1.x; As[skk+5][srow]=a1.y; As[skk+6][srow]=a1.z; As[skk+7][srow]=a1.w;
      Bs[skk+0][srow]=b0.x; Bs[skk+1][srow]=b0.y; Bs[skk+2][srow]=b0.z; Bs[skk+3][srow]=b0.w;
      Bs[skk+4][srow]=b1.x; Bs[skk+5][srow]=b1.y; Bs[skk+6][srow]=b1.z; Bs[skk+7][srow]=b1.w;
      __syncthreads();
      #pragma unroll
      for (int kk=0; kk<TKc; ++kk){
        float4 av = *(const float4*)&As[kk][ty*4];
        float4 bv = *(const float4*)&Bs[kk][tx*4];
        float a_[4] = {av.x, av.y, av.z, av.w};
        float b_[4] = {bv.x, bv.y, bv.z, bv.w};
        #pragma unroll
        for (int i=0;i<4;i++)
          #pragma unroll
          for (int j=0;j<4;j++)
            acc[i][j] += a_[i]*b_[j];
      }
    }
    #pragma unroll
    for (int j=0;j<4;j++){
      int n = n0 + tx*4 + j;
      float yy = y2[n];
      #pragma unroll
      for (int i=0;i<4;i++){
        float d2 = fmaxf(px2[i] + yy - 2.f*acc[i][j], 0.f);
        if (d2 < bestVal[i]){ bestVal[i]=d2; bestIdx[i]=n; }
      }
    }
  }
  #pragma unroll
  for (int i=0;i<4;i++){
    u64 pk = (((u64)__float_as_uint(bestVal[i]))<<32) | (u32)bestIdx[i];
    #pragma unroll
    for (int md=1; md<16; md<<=1){
      u64 o = __shfl_xor(pk, md);
      if (o < pk) pk = o;
    }
    int pr = m0 + ty*4 + i;
    if (tx==0 && pr < NP) atomicMin(&packed[pr], pk);
  }
}

__global__ void k_unpack(const u64* __restrict__ packed, float* __restrict__ patch_d, int* __restrict__ loc){
  int t = blockIdx.x*256 + threadIdx.x;
  if (t < NP){
    u64 v = packed[t];
    patch_d[t] = sqrtf(__uint_as_float((u32)(v>>32)));
    loc[t] = (int)(v & 0xffffffffu);
  }
}

// ---------------- per-batch argmax of patch scores ----------------
__global__ void k_argmax(const float* __restrict__ patch_d, const int* __restrict__ loc,
                         int* __restrict__ sel_mp, float* __restrict__ sel_score, int* __restrict__ sel_nn){
  int b = blockIdx.x;
  int tid = threadIdx.x;
  __shared__ u64 red[4];
  u64 best = 0;
  for (int p = tid; p < HO2*HO2; p += 256){
    float v = patch_d[b*HO2*HO2 + p];
    u64 pk = (((u64)__float_as_uint(v))<<32) | (u32)(HO2*HO2 - p);  // tie -> smaller p wins on max
    if (pk > best) best = pk;
  }
  int lane = tid & 63, w = tid >> 6;
  #pragma unroll
  for (int d=32; d; d>>=1){ u64 o = __shfl_down(best, d); if (o > best) best = o; }
  if (lane==0) red[w] = best;
  __syncthreads();
  if (tid==0){
    u64 bb = red[0];
    for (int q=1;q<4;q++) if (red[q] > bb) bb = red[q];
    int p = HO2*HO2 - (int)(bb & 0xffffffffu);
    sel_mp[b] = p;
    sel_score[b] = __uint_as_float((u32)(bb>>32));
    sel_nn[b] = loc[b*HO2*HO2 + p];
  }
}

// ---------------- d2(nn_sample[b], bank[m]) for all b,m ----------------
__global__ __launch_bounds__(256) void k_dbank(const float* __restrict__ bank, const float* __restrict__ y2,
    const int* __restrict__ sel_nn, float* __restrict__ d_bank){
  int wave = threadIdx.x >> 6, lane = threadIdx.x & 63;
  int m = blockIdx.x*4 + wave;
  if (m >= NM) return;
  int nn[NB];
  #pragma unroll
  for (int b=0;b<NB;b++) nn[b] = sel_nn[b];
  const float4* pm = (const float4*)(bank + (size_t)m*CC);
  float acc[NB];
  #pragma unroll
  for (int b=0;b<NB;b++) acc[b] = 0.f;
  for (int it=0; it<6; ++it){
    float4 v = pm[it*64 + lane];
    #pragma unroll
    for (int b=0;b<NB;b++){
      const float4* pn = (const float4*)(bank + (size_t)nn[b]*CC);
      float4 u = pn[it*64 + lane];
      acc[b] += v.x*u.x + v.y*u.y + v.z*u.z + v.w*u.w;
    }
  }
  #pragma unroll
  for (int b=0;b<NB;b++){
    float s = warp_sum(acc[b]);
    if (lane==0) d_bank[(size_t)b*NM + m] = fmaxf(y2[nn[b]] + y2[m] - 2.f*s, 0.f);
  }
}

// ---------------- top-9 + anomaly score ----------------
__global__ __launch_bounds__(256) void k_score(const float* __restrict__ d_bank, const float* __restrict__ bank,
    const float* __restrict__ emb, const float* __restrict__ x2, const float* __restrict__ y2,
    const int* __restrict__ sel_mp, const float* __restrict__ sel_score, float* __restrict__ out_score){
  int b = blockIdx.x, tid = threadIdx.x;
  __shared__ int sel[NKNN];
  __shared__ u64 red[4];
  __shared__ float fred[4];
  __shared__ float sumexp_s;
  for (int k=0; k<NKNN; ++k){
    u64 best = ~0ull;
    for (int m = tid; m < NM; m += 256){
      bool skip = false;
      for (int q=0; q<k; ++q) if (sel[q]==m) skip = true;
      if (skip) continue;
      float v = d_bank[(size_t)b*NM + m];
      u64 pk = (((u64)__float_as_uint(v))<<32) | (u32)m;
      if (pk < best) best = pk;
    }
    int lane = tid & 63, w = tid >> 6;
    #pragma unroll
    for (int d=32; d; d>>=1){ u64 o = __shfl_down(best, d); if (o < best) best = o; }
    if (lane==0) red[w] = best;
    __syncthreads();
    if (tid==0){
      u64 bb = red[0];
      for (int q=1;q<4;q++) if (red[q] < bb) bb = red[q];
      sel[k] = (int)(bb & 0xffffffffu);
    }
    __syncthreads();
  }
  int mp = sel_mp[b];
  const float* fv = emb + (size_t)(b*HO2*HO2 + mp)*CC;
  float fx2 = x2[b*HO2*HO2 + mp];
  if (tid==0) sumexp_s = 0.f;
  __syncthreads();
  for (int k=0;k<NKNN;++k){
    const float* sv = bank + (size_t)sel[k]*CC;
    float part = 0.f;
    for (int i = tid; i < CC; i += 256) part += fv[i]*sv[i];
    int lane = tid & 63, w = tid >> 6;
    part = warp_sum(part);
    if (lane==0) fred[w] = part;
    __syncthreads();
    if (tid==0){
      float dot = fred[0]+fred[1]+fred[2]+fred[3];
      float d2 = fmaxf(fx2 + y2[sel[k]] - 2.f*dot, 0.f);
      sumexp_s += expf(sqrtf(d2));
    }
    __syncthreads();
  }
  if (tid==0){
    float s = sel_score[b];
    out_score[b] = (1.f - expf(s)/sumexp_s) * s;
  }
}

// ---------------- anomaly map: bilinear 27 -> 224, then separable gaussian ----------------
__global__ void k_amap_bilinear(const float* __restrict__ patch_d, float* __restrict__ amap){
  int t = blockIdx.x*256 + threadIdx.x;
  if (t >= AMAP_N) return;
  int x = t % OH; int r = t / OH;
  int y = r % OH; int b = r / OH;
  float fy = (y + 0.5f) * (27.f/224.f) - 0.5f;
  float fx = (x + 0.5f) * (27.f/224.f) - 0.5f;
  int y0 = (int)floorf(fy); float wy = fy - (float)y0;
  int x0 = (int)floorf(fx); float wx = fx - (float)x0;
  int y0c = min(max(y0,0),HO2-1), y1c = min(max(y0+1,0),HO2-1);
  int x0c = min(max(x0,0),HO2-1), x1c = min(max(x0+1,0),HO2-1);
  const float* p = patch_d + b*HO2*HO2;
  float v = (1.f-wy)*((1.f-wx)*p[y0c*HO2+x0c] + wx*p[y0c*HO2+x1c])
          + wy*((1.f-wx)*p[y1c*HO2+x0c] + wx*p[y1c*HO2+x1c]);
  amap[t] = v;
}

__global__ void k_blur_h(const float* __restrict__ in, float* __restrict__ out, GW gw){
  int t = blockIdx.x*256 + threadIdx.x;
  if (t >= AMAP_N) return;
  int x = t % OH; int rest = t / OH;
  const float* row = in + (size_t)rest*OH;
  float s = 0.f;
  #pragma unroll
  for (int k=0;k<33;++k){
    int xx = x + k - 16;
    xx = (xx < 0) ? -xx : xx;
    xx = (xx > OH-1) ? (2*(OH-1) - xx) : xx;
    s += gw.w[k]*row[xx];
  }
  out[t] = s;
}

__global__ void k_blur_v(const float* __restrict__ in, float* __restrict__ out, GW gw){
  int t = blockIdx.x*256 + threadIdx.x;
  if (t >= AMAP_N) return;
  int x = t % OH; int r = t / OH;
  int y = r % OH; int b = r / OH;
  const float* img = in + (size_t)b*OH*OH;
  float s = 0.f;
  #pragma unroll
  for (int k=0;k<33;++k){
    int yy = y + k - 16;
    yy = (yy < 0) ? -yy : yy;
    yy = (yy > OH-1) ? (2*(OH-1) - yy) : yy;
    s += gw.w[k]*img[(size_t)yy*OH + x];
  }
  out[t] = s;
}

extern "C" void kernel_launch(void* const* d_in, const int* in_sizes, int n_in,
                              void* d_out, int out_size, void* d_ws, size_t ws_size,
                              hipStream_t stream){
  const float* f2   = (const float*)d_in[0];
  const float* f3   = (const float*)d_in[1];
  const float* bank = (const float*)d_in[2];
  float* out = (float*)d_out;

  char* ws = (char*)d_ws;
  size_t off = 0;
  auto alloc = [&](size_t bytes)->char*{ char* p = ws + off; off += (bytes + 255) & ~(size_t)255; return p; };
  float* emb      = (float*)alloc((size_t)NP*CC*4);
  float* f3p      = (float*)alloc((size_t)NB*HO3*HO3*C3*4);
  float* y2       = (float*)alloc((size_t)NM*4);
  float* x2       = (float*)alloc((size_t)NP*4);
  u64*   packed   = (u64*)  alloc((size_t)NP*8);
  float* patch_d  = (float*)alloc((size_t)NP*4);
  int*   loc      = (int*)  alloc((size_t)NP*4);
  float* d_bank   = (float*)alloc((size_t)NB*NM*4);
  int*   sel_mp   = (int*)  alloc(NB*4);
  float* sel_scr  = (float*)alloc(NB*4);
  int*   sel_nn   = (int*)  alloc(NB*4);
  float* amap1    = (float*)alloc((size_t)AMAP_N*4);
  float* amap2    = (float*)alloc((size_t)AMAP_N*4);

  GW gw;
  { float s=0.f; for(int i=0;i<33;i++){ float xx=(float)i-16.f; gw.w[i]=expf(-0.5f*(xx/4.f)*(xx/4.f)); s+=gw.w[i]; }
    for(int i=0;i<33;i++) gw.w[i]/=s; }

  k_avgpool2<<<(NB*HO2*HO2*C2+255)/256,256,0,stream>>>(f2, emb);
  k_avgpool3<<<(NB*HO3*HO3*C3+255)/256,256,0,stream>>>(f3, f3p);
  k_upsample3<<<(NB*HO2*HO2*C3+255)/256,256,0,stream>>>(f3p, emb);
  k_rowsumsq<<<(NM+3)/4,256,0,stream>>>(bank, y2, NM);
  k_rowsumsq<<<(NP+3)/4,256,0,stream>>>(emb, x2, NP);
  k_init<<<(NP+255)/256,256,0,stream>>>(packed);
  dim3 g((NP+TM-1)/TM, (NM/TN)/NTILE);
  k_distmin<<<g,256,0,stream>>>(emb, bank, x2, y2, packed);
  k_unpack<<<(NP+255)/256,256,0,stream>>>(packed, patch_d, loc);
  k_argmax<<<NB,256,0,stream>>>(patch_d, loc, sel_mp, sel_scr, sel_nn);
  k_dbank<<<(NM+3)/4,256,0,stream>>>(bank, y2, sel_nn, d_bank);
  k_score<<<NB,256,0,stream>>>(d_bank, bank, emb, x2, y2, sel_mp, sel_scr, out + AMAP_N);
  k_amap_bilinear<<<(AMAP_N+255)/256,256,0,stream>>>(patch_d, amap1);
  k_blur_h<<<(AMAP_N+255)/256,256,0,stream>>>(amap1, amap2, gw);
  k_blur_v<<<(AMAP_N+255)/256,256,0,stream>>>(amap2, out, gw);
}

// Round 2
// 2641.509 us; speedup vs baseline: 3.5250x; 3.5250x over previous
//
#include <hip/hip_runtime.h>
#include <math.h>

#define NB 8
#define C2 512
#define C3 1024
#define HIN2 28
#define HIN3 14
#define HO2 27
#define HO3 13
#define CC 1536
#define NP (NB*HO2*HO2)   /* 5832 */
#define NM 32000
#define NKNN 9
#define OH 224
#define AMAP_N (NB*OH*OH) /* 401408 */
#define NTILE 10          /* N-tiles (128 wide) per block; 250 tiles -> 25 y-blocks */

typedef unsigned long long u64;
typedef unsigned int u32;
typedef __attribute__((ext_vector_type(8))) short bf16x8;
typedef __attribute__((ext_vector_type(4))) float f32x4;

struct GW { float w[33]; };

__device__ __forceinline__ float warp_sum(float v){
  #pragma unroll
  for (int off=32; off; off>>=1) v += __shfl_down(v, off);
  return v;
}

__device__ __forceinline__ ushort f2bf(float f){
  u32 u = __float_as_uint(f);
  u32 r = (u + 0x7FFFu + ((u>>16)&1u)) >> 16;
  return (ushort)r;
}
__device__ __forceinline__ float bf2f(ushort b){
  return __uint_as_float(((u32)b)<<16);
}

#define GLDS(g, l) __builtin_amdgcn_global_load_lds((const __attribute__((address_space(1))) void*)(g), (__attribute__((address_space(3))) void*)(l), 16, 0, 0)

// ---------------- avg pool k=4,s=1,p=1 (count_include_pad -> /16), write bf16 embedding ----------------
__global__ void k_avgpool2(const float* __restrict__ in, ushort* __restrict__ embB){
  int t = blockIdx.x*256 + threadIdx.x;
  if (t >= NB*HO2*HO2*C2) return;
  int c = t % C2; int r = t / C2;
  int j = r % HO2; r /= HO2;
  int i = r % HO2; int b = r / HO2;
  const float* plane = in + ((size_t)(b*C2 + c)*HIN2)*HIN2;
  float s = 0.f;
  #pragma unroll
  for (int di=0; di<4; ++di){
    int y = i - 1 + di;
    if ((unsigned)y >= HIN2) continue;
    #pragma unroll
    for (int dj=0; dj<4; ++dj){
      int x = j - 1 + dj;
      if ((unsigned)x < HIN2) s += plane[y*HIN2 + x];
    }
  }
  embB[((size_t)((b*HO2 + i)*HO2 + j))*CC + c] = f2bf(s * (1.f/16.f));
}

__global__ void k_avgpool3(const float* __restrict__ in, float* __restrict__ f3p){
  int t = blockIdx.x*256 + threadIdx.x;
  if (t >= NB*HO3*HO3*C3) return;
  int c = t % C3; int r = t / C3;
  int j = r % HO3; r /= HO3;
  int i = r % HO3; int b = r / HO3;
  const float* plane = in + ((size_t)(b*C3 + c)*HIN3)*HIN3;
  float s = 0.f;
  #pragma unroll
  for (int di=0; di<4; ++di){
    int y = i - 1 + di;
    if ((unsigned)y >= HIN3) continue;
    #pragma unroll
    for (int dj=0; dj<4; ++dj){
      int x = j - 1 + dj;
      if ((unsigned)x < HIN3) s += plane[y*HIN3 + x];
    }
  }
  f3p[((size_t)((b*HO3 + i)*HO3 + j))*C3 + c] = s * (1.f/16.f);
}

// ---------------- bilinear 13x13 -> 27x27 (half-pixel, clamp taps), write bf16 embedding ----------------
__global__ void k_upsample3(const float* __restrict__ f3p, ushort* __restrict__ embB){
  int t = blockIdx.x*256 + threadIdx.x;
  if (t >= NB*HO2*HO2*C3) return;
  int c = t % C3; int r = t / C3;
  int ox = r % HO2; r /= HO2;
  int oy = r % HO2; int b = r / HO2;
  float fy = (oy + 0.5f) * (13.f/27.f) - 0.5f;
  float fx = (ox + 0.5f) * (13.f/27.f) - 0.5f;
  int y0 = (int)floorf(fy); float wy = fy - (float)y0;
  int x0 = (int)floorf(fx); float wx = fx - (float)x0;
  int y0c = min(max(y0,0), HO3-1), y1c = min(max(y0+1,0), HO3-1);
  int x0c = min(max(x0,0), HO3-1), x1c = min(max(x0+1,0), HO3-1);
  const float* base = f3p + (size_t)(b*HO3*HO3)*C3;
  float v00 = base[(size_t)(y0c*HO3 + x0c)*C3 + c];
  float v01 = base[(size_t)(y0c*HO3 + x1c)*C3 + c];
  float v10 = base[(size_t)(y1c*HO3 + x0c)*C3 + c];
  float v11 = base[(size_t)(y1c*HO3 + x1c)*C3 + c];
  float v = (1.f-wy)*((1.f-wx)*v00 + wx*v01) + wy*((1.f-wx)*v10 + wx*v11);
  embB[((size_t)((b*HO2 + oy)*HO2 + ox))*CC + C2 + c] = f2bf(v);
}

// ---------------- fp32 -> bf16 bank conversion (8 elems/thread, 16B stores) ----------------
__global__ void k_cvt_bank(const float* __restrict__ bank, ushort* __restrict__ bankB){
  size_t t = (size_t)blockIdx.x*256 + threadIdx.x;
  if (t >= ((size_t)NM*CC)/8) return;
  const float4* src = (const float4*)bank + t*2;
  float4 a = src[0], b = src[1];
  uint4 o;
  o.x = ((u32)f2bf(a.y)<<16) | f2bf(a.x);
  o.y = ((u32)f2bf(a.w)<<16) | f2bf(a.z);
  o.z = ((u32)f2bf(b.y)<<16) | f2bf(b.x);
  o.w = ((u32)f2bf(b.w)<<16) | f2bf(b.z);
  ((uint4*)bankB)[t] = o;
}

// ---------------- row sums of squares ----------------
__global__ void k_rowsumsq(const float* __restrict__ src, float* __restrict__ dst, int rows){
  int wave = threadIdx.x >> 6;
  int lane = threadIdx.x & 63;
  int r = blockIdx.x*4 + wave;
  if (r >= rows) return;
  const float4* p = (const float4*)(src + (size_t)r*CC);
  float s = 0.f;
  #pragma unroll
  for (int it=0; it<6; ++it){
    float4 v = p[it*64 + lane];
    s += v.x*v.x + v.y*v.y + v.z*v.z + v.w*v.w;
  }
  s = warp_sum(s);
  if (lane==0) dst[r] = s;
}

__global__ void k_rowsumsq_bf(const ushort* __restrict__ src, float* __restrict__ dst, int rows){
  int wave = threadIdx.x >> 6;
  int lane = threadIdx.x & 63;
  int r = blockIdx.x*4 + wave;
  if (r >= rows) return;
  const uint4* p = (const uint4*)(src + (size_t)r*CC);
  float s = 0.f;
  #pragma unroll
  for (int it=0; it<3; ++it){
    uint4 v = p[it*64 + lane];
    u32 ws_[4] = {v.x, v.y, v.z, v.w};
    #pragma unroll
    for (int q=0;q<4;q++){
      float lo = __uint_as_float(ws_[q]<<16);
      float hi = __uint_as_float(ws_[q]&0xFFFF0000u);
      s += lo*lo + hi*hi;
    }
  }
  s = warp_sum(s);
  if (lane==0) dst[r] = s;
}

__global__ void k_init(u64* __restrict__ packed){
  int t = blockIdx.x*256 + threadIdx.x;
  if (t < NP) packed[t] = ~0ull;
}

// ---------------- fused bf16 MFMA distance GEMM + min/argmin ----------------
// C = embB(5832xK) . bankB(32000xK)^T ; d2 = x2 + y2 - 2C ; min over n per row.
// m97 structure: 128x128 tile, BK=32, 4 waves (2x2 of 64x64), global_load_lds x4.
__global__ __launch_bounds__(256) void k_distmin_mfma(
    const ushort* __restrict__ A, const ushort* __restrict__ B,
    const float* __restrict__ x2, const float* __restrict__ y2,
    u64* __restrict__ packed)
{
  __shared__ ushort As[128*32];
  __shared__ ushort Bs[128*32];
  const int tid = threadIdx.x;
  const int lane = tid & 63;
  const int w = tid >> 6;          // wave 0..3
  const int wr = w >> 1, wc = w & 1;
  const int m0 = blockIdx.x * 128;

  const int srow = tid >> 2;       // 0..63: staged row within 64-row half
  const int spart = tid & 3;       // 16B quarter of a 64B (32-elem) row

  const int arow0 = min(m0 + srow, NP-1);
  const int arow1 = min(m0 + 64 + srow, NP-1);
  const ushort* aSrc0 = A + (size_t)arow0*CC + spart*8;
  const ushort* aSrc1 = A + (size_t)arow1*CC + spart*8;
  ushort* aDst0 = As + w*512;         // wave-uniform LDS bases (bytes: w*1024)
  ushort* aDst1 = As + 2048 + w*512;
  ushort* bDst0 = Bs + w*512;
  ushort* bDst1 = Bs + 2048 + w*512;

  const int ccol = lane & 15;      // C col within 16x16 frag
  const int cgrp = lane >> 4;      // C row group

  float xv[4][4];
  #pragma unroll
  for (int mi=0;mi<4;mi++)
    #pragma unroll
    for (int r=0;r<4;r++)
      xv[mi][r] = x2[min(m0 + wr*64 + mi*16 + cgrp*4 + r, NP-1)];

  u64 best[4][4];
  #pragma unroll
  for (int mi=0;mi<4;mi++)
    #pragma unroll
    for (int r=0;r<4;r++) best[mi][r] = ~0ull;

  for (int bt=0; bt<NTILE; ++bt){
    const int n0 = (blockIdx.y*NTILE + bt) * 128;
    const ushort* bSrc0 = B + (size_t)(n0 + srow)*CC + spart*8;
    const ushort* bSrc1 = B + (size_t)(n0 + 64 + srow)*CC + spart*8;
    f32x4 acc[4][4];
    #pragma unroll
    for (int mi=0;mi<4;mi++)
      #pragma unroll
      for (int ni=0;ni<4;ni++)
        acc[mi][ni] = (f32x4){0.f,0.f,0.f,0.f};

    for (int k0=0; k0<CC; k0+=32){
      __syncthreads();              // protect LDS from overwrite while prior reads in flight
      GLDS(aSrc0 + k0, aDst0);
      GLDS(aSrc1 + k0, aDst1);
      GLDS(bSrc0 + k0, bDst0);
      GLDS(bSrc1 + k0, bDst1);
      __syncthreads();              // compiler drains vmcnt before s_barrier
      bf16x8 av[4], bv[4];
      #pragma unroll
      for (int mi=0;mi<4;mi++)
        av[mi] = *(const bf16x8*)&As[(wr*64 + mi*16 + ccol)*32 + cgrp*8];
      #pragma unroll
      for (int ni=0;ni<4;ni++)
        bv[ni] = *(const bf16x8*)&Bs[(wc*64 + ni*16 + ccol)*32 + cgrp*8];
      #pragma unroll
      for (int mi=0;mi<4;mi++)
        #pragma unroll
        for (int ni=0;ni<4;ni++)
          acc[mi][ni] = __builtin_amdgcn_mfma_f32_16x16x32_bf16(av[mi], bv[ni], acc[mi][ni], 0, 0, 0);
    }

    // fold d2 = x2 + y2 - 2*dot into per-lane running min
    #pragma unroll
    for (int ni=0;ni<4;ni++){
      const int n = n0 + wc*64 + ni*16 + ccol;
      const float yy = y2[n];
      #pragma unroll
      for (int mi=0;mi<4;mi++)
        #pragma unroll
        for (int r=0;r<4;r++){
          float d2 = fmaxf(xv[mi][r] + yy - 2.f*acc[mi][ni][r], 0.f);
          u64 pk = (((u64)__float_as_uint(d2))<<32) | (u32)n;
          if (pk < best[mi][r]) best[mi][r] = pk;
        }
    }
  }

  // reduce across the 16 lanes sharing each C-row, then one atomicMin per row
  #pragma unroll
  for (int mi=0;mi<4;mi++)
    #pragma unroll
    for (int r=0;r<4;r++){
      u64 pk = best[mi][r];
      #pragma unroll
      for (int md=1; md<16; md<<=1){
        u64 o = __shfl_xor(pk, md);
        if (o < pk) pk = o;
      }
      const int row = m0 + wr*64 + mi*16 + cgrp*4 + r;
      if (ccol==0 && row < NP) atomicMin(&packed[row], pk);
    }
}

__global__ void k_unpack(const u64* __restrict__ packed, float* __restrict__ patch_d, int* __restrict__ loc){
  int t = blockIdx.x*256 + threadIdx.x;
  if (t < NP){
    u64 v = packed[t];
    patch_d[t] = sqrtf(__uint_as_float((u32)(v>>32)));
    loc[t] = (int)(v & 0xffffffffu);
  }
}

// ---------------- per-batch argmax of patch scores ----------------
__global__ void k_argmax(const float* __restrict__ patch_d, const int* __restrict__ loc,
                         int* __restrict__ sel_mp, float* __restrict__ sel_score, int* __restrict__ sel_nn){
  int b = blockIdx.x;
  int tid = threadIdx.x;
  __shared__ u64 red[4];
  u64 best = 0;
  for (int p = tid; p < HO2*HO2; p += 256){
    float v = patch_d[b*HO2*HO2 + p];
    u64 pk = (((u64)__float_as_uint(v))<<32) | (u32)(HO2*HO2 - p);  // tie -> smaller p wins on max
    if (pk > best) best = pk;
  }
  int lane = tid & 63, w = tid >> 6;
  #pragma unroll
  for (int d=32; d; d>>=1){ u64 o = __shfl_down(best, d); if (o > best) best = o; }
  if (lane==0) red[w] = best;
  __syncthreads();
  if (tid==0){
    u64 bb = red[0];
    for (int q=1;q<4;q++) if (red[q] > bb) bb = red[q];
    int p = HO2*HO2 - (int)(bb & 0xffffffffu);
    sel_mp[b] = p;
    sel_score[b] = __uint_as_float((u32)(bb>>32));
    sel_nn[b] = loc[b*HO2*HO2 + p];
  }
}

// ---------------- d2(nn_sample[b], bank[m]) for all b,m (fp32) ----------------
__global__ __launch_bounds__(256) void k_dbank(const float* __restrict__ bank, const float* __restrict__ y2,
    const int* __restrict__ sel_nn, float* __restrict__ d_bank){
  int wave = threadIdx.x >> 6, lane = threadIdx.x & 63;
  int m = blockIdx.x*4 + wave;
  if (m >= NM) return;
  int nn[NB];
  #pragma unroll
  for (int b=0;b<NB;b++) nn[b] = sel_nn[b];
  const float4* pm = (const float4*)(bank + (size_t)m*CC);
  float acc[NB];
  #pragma unroll
  for (int b=0;b<NB;b++) acc[b] = 0.f;
  for (int it=0; it<6; ++it){
    float4 v = pm[it*64 + lane];
    #pragma unroll
    for (int b=0;b<NB;b++){
      const float4* pn = (const float4*)(bank + (size_t)nn[b]*CC);
      float4 u = pn[it*64 + lane];
      acc[b] += v.x*u.x + v.y*u.y + v.z*u.z + v.w*u.w;
    }
  }
  #pragma unroll
  for (int b=0;b<NB;b++){
    float s = warp_sum(acc[b]);
    if (lane==0) d_bank[(size_t)b*NM + m] = fmaxf(y2[nn[b]] + y2[m] - 2.f*s, 0.f);
  }
}

// ---------------- top-9 + anomaly score ----------------
__global__ __launch_bounds__(256) void k_score(const float* __restrict__ d_bank, const float* __restrict__ bank,
    const ushort* __restrict__ embB, const float* __restrict__ x2, const float* __restrict__ y2,
    const int* __restrict__ sel_mp, const float* __restrict__ sel_score, float* __restrict__ out_score){
  int b = blockIdx.x, tid = threadIdx.x;
  __shared__ int sel[NKNN];
  __shared__ u64 red[4];
  __shared__ float fred[4];
  __shared__ float sumexp_s;
  for (int k=0; k<NKNN; ++k){
    u64 best = ~0ull;
    for (int m = tid; m < NM; m += 256){
      bool skip = false;
      for (int q=0; q<k; ++q) if (sel[q]==m) skip = true;
      if (skip) continue;
      float v = d_bank[(size_t)b*NM + m];
      u64 pk = (((u64)__float_as_uint(v))<<32) | (u32)m;
      if (pk < best) best = pk;
    }
    int lane = tid & 63, w = tid >> 6;
    #pragma unroll
    for (int d=32; d; d>>=1){ u64 o = __shfl_down(best, d); if (o < best) best = o; }
    if (lane==0) red[w] = best;
    __syncthreads();
    if (tid==0){
      u64 bb = red[0];
      for (int q=1;q<4;q++) if (red[q] < bb) bb = red[q];
      sel[k] = (int)(bb & 0xffffffffu);
    }
    __syncthreads();
  }
  int mp = sel_mp[b];
  const ushort* fv = embB + (size_t)(b*HO2*HO2 + mp)*CC;
  float fx2 = x2[b*HO2*HO2 + mp];
  if (tid==0) sumexp_s = 0.f;
  __syncthreads();
  for (int k=0;k<NKNN;++k){
    const float* sv = bank + (size_t)sel[k]*CC;
    float part = 0.f;
    for (int i = tid; i < CC; i += 256) part += bf2f(fv[i])*sv[i];
    int lane = tid & 63, w = tid >> 6;
    part = warp_sum(part);
    if (lane==0) fred[w] = part;
    __syncthreads();
    if (tid==0){
      float dot = fred[0]+fred[1]+fred[2]+fred[3];
      float d2 = fmaxf(fx2 + y2[sel[k]] - 2.f*dot, 0.f);
      sumexp_s += expf(sqrtf(d2));
    }
    __syncthreads();
  }
  if (tid==0){
    float s = sel_score[b];
    out_score[b] = (1.f - expf(s)/sumexp_s) * s;
  }
}

// ---------------- anomaly map: bilinear 27 -> 224, then separable gaussian ----------------
__global__ void k_amap_bilinear(const float* __restrict__ patch_d, float* __restrict__ amap){
  int t = blockIdx.x*256 + threadIdx.x;
  if (t >= AMAP_N) return;
  int x = t % OH; int r = t / OH;
  int y = r % OH; int b = r / OH;
  float fy = (y + 0.5f) * (27.f/224.f) - 0.5f;
  float fx = (x + 0.5f) * (27.f/224.f) - 0.5f;
  int y0 = (int)floorf(fy); float wy = fy - (float)y0;
  int x0 = (int)floorf(fx); float wx = fx - (float)x0;
  int y0c = min(max(y0,0),HO2-1), y1c = min(max(y0+1,0),HO2-1);
  int x0c = min(max(x0,0),HO2-1), x1c = min(max(x0+1,0),HO2-1);
  const float* p = patch_d + b*HO2*HO2;
  float v = (1.f-wy)*((1.f-wx)*p[y0c*HO2+x0c] + wx*p[y0c*HO2+x1c])
          + wy*((1.f-wx)*p[y1c*HO2+x0c] + wx*p[y1c*HO2+x1c]);
  amap[t] = v;
}

__global__ void k_blur_h(const float* __restrict__ in, float* __restrict__ out, GW gw){
  int t = blockIdx.x*256 + threadIdx.x;
  if (t >= AMAP_N) return;
  int x = t % OH; int rest = t / OH;
  const float* row = in + (size_t)rest*OH;
  float s = 0.f;
  #pragma unroll
  for (int k=0;k<33;++k){
    int xx = x + k - 16;
    xx = (xx < 0) ? -xx : xx;
    xx = (xx > OH-1) ? (2*(OH-1) - xx) : xx;
    s += gw.w[k]*row[xx];
  }
  out[t] = s;
}

__global__ void k_blur_v(const float* __restrict__ in, float* __restrict__ out, GW gw){
  int t = blockIdx.x*256 + threadIdx.x;
  if (t >= AMAP_N) return;
  int x = t % OH; int r = t / OH;
  int y = r % OH; int b = r / OH;
  const float* img = in + (size_t)b*OH*OH;
  float s = 0.f;
  #pragma unroll
  for (int k=0;k<33;++k){
    int yy = y + k - 16;
    yy = (yy < 0) ? -yy : yy;
    yy = (yy > OH-1) ? (2*(OH-1) - yy) : yy;
    s += gw.w[k]*img[(size_t)yy*OH + x];
  }
  out[t] = s;
}

extern "C" void kernel_launch(void* const* d_in, const int* in_sizes, int n_in,
                              void* d_out, int out_size, void* d_ws, size_t ws_size,
                              hipStream_t stream){
  const float* f2   = (const float*)d_in[0];
  const float* f3   = (const float*)d_in[1];
  const float* bank = (const float*)d_in[2];
  float* out = (float*)d_out;

  char* ws = (char*)d_ws;
  size_t off = 0;
  auto alloc = [&](size_t bytes)->char*{ char* p = ws + off; off += (bytes + 255) & ~(size_t)255; return p; };
  ushort* embB    = (ushort*)alloc((size_t)NP*CC*2);
  ushort* bankB   = (ushort*)alloc((size_t)NM*CC*2);
  float* f3p      = (float*)alloc((size_t)NB*HO3*HO3*C3*4);
  float* y2       = (float*)alloc((size_t)NM*4);
  float* x2       = (float*)alloc((size_t)NP*4);
  u64*   packed   = (u64*)  alloc((size_t)NP*8);
  float* patch_d  = (float*)alloc((size_t)NP*4);
  int*   loc      = (int*)  alloc((size_t)NP*4);
  float* d_bank   = (float*)alloc((size_t)NB*NM*4);
  int*   sel_mp   = (int*)  alloc(NB*4);
  float* sel_scr  = (float*)alloc(NB*4);
  int*   sel_nn   = (int*)  alloc(NB*4);
  float* amap1    = (float*)alloc((size_t)AMAP_N*4);
  float* amap2    = (float*)alloc((size_t)AMAP_N*4);

  GW gw;
  { float s=0.f; for(int i=0;i<33;i++){ float xx=(float)i-16.f; gw.w[i]=expf(-0.5f*(xx/4.f)*(xx/4.f)); s+=gw.w[i]; }
    for(int i=0;i<33;i++) gw.w[i]/=s; }

  k_avgpool2<<<(NB*HO2*HO2*C2+255)/256,256,0,stream>>>(f2, embB);
  k_avgpool3<<<(NB*HO3*HO3*C3+255)/256,256,0,stream>>>(f3, f3p);
  k_upsample3<<<(NB*HO2*HO2*C3+255)/256,256,0,stream>>>(f3p, embB);
  k_cvt_bank<<<(int)(((size_t)NM*CC/8 + 255)/256),256,0,stream>>>(bank, bankB);
  k_rowsumsq<<<(NM+3)/4,256,0,stream>>>(bank, y2, NM);
  k_rowsumsq_bf<<<(NP+3)/4,256,0,stream>>>(embB, x2, NP);
  k_init<<<(NP+255)/256,256,0,stream>>>(packed);
  dim3 g((NP+127)/128, (NM/128)/NTILE);
  k_distmin_mfma<<<g,256,0,stream>>>(embB, bankB, x2, y2, packed);
  k_unpack<<<(NP+255)/256,256,0,stream>>>(packed, patch_d, loc);
  k_argmax<<<NB,256,0,stream>>>(patch_d, loc, sel_mp, sel_scr, sel_nn);
  k_dbank<<<(NM+3)/4,256,0,stream>>>(bank, y2, sel_nn, d_bank);
  k_score<<<NB,256,0,stream>>>(d_bank, bank, embB, x2, y2, sel_mp, sel_scr, out + AMAP_N);
  k_amap_bilinear<<<(AMAP_N+255)/256,256,0,stream>>>(patch_d, amap1);
  k_blur_h<<<(AMAP_N+255)/256,256,0,stream>>>(amap1, amap2, gw);
  k_blur_v<<<(AMAP_N+255)/256,256,0,stream>>>(amap2, out, gw);
}

// Round 3
// 1191.660 us; speedup vs baseline: 7.8138x; 2.2167x over previous
//
#include <hip/hip_runtime.h>
#include <math.h>

#define NB 8
#define C2 512
#define C3 1024
#define HIN2 28
#define HIN3 14
#define HO2 27
#define HO3 13
#define CC 1536
#define NP (NB*HO2*HO2)   /* 5832 */
#define NM 32000
#define NKNN 9
#define OH 224
#define AMAP_N (NB*OH*OH) /* 401408 */

/* 256x256 tile GEMM geometry */
#define BM 256
#define BN 256
#define BK 64
#define KT (CC/BK)        /* 24 */
#define MB_CNT ((NP+BM-1)/BM)   /* 23 */
#define NB_CNT (NM/BN)          /* 125 */
#define NWG (MB_CNT*NB_CNT)     /* 2875 */

typedef unsigned long long u64;
typedef unsigned int u32;
typedef __attribute__((ext_vector_type(8))) short bf16x8;
typedef __attribute__((ext_vector_type(4))) float f32x4;

struct GW { float w[33]; };

__device__ __forceinline__ float warp_sum(float v){
  #pragma unroll
  for (int off=32; off; off>>=1) v += __shfl_down(v, off);
  return v;
}

__device__ __forceinline__ ushort f2bf(float f){
  u32 u = __float_as_uint(f);
  u32 r = (u + 0x7FFFu + ((u>>16)&1u)) >> 16;
  return (ushort)r;
}
__device__ __forceinline__ float bf2f(ushort b){
  return __uint_as_float(((u32)b)<<16);
}

#define GLDS(g, l) __builtin_amdgcn_global_load_lds((const __attribute__((address_space(1))) void*)(g), (__attribute__((address_space(3))) void*)(l), 16, 0, 0)

// ---------------- avg pool k=4,s=1,p=1, write bf16 embedding ----------------
__global__ void k_avgpool2(const float* __restrict__ in, ushort* __restrict__ embB){
  int t = blockIdx.x*256 + threadIdx.x;
  if (t >= NB*HO2*HO2*C2) return;
  int c = t % C2; int r = t / C2;
  int j = r % HO2; r /= HO2;
  int i = r % HO2; int b = r / HO2;
  const float* plane = in + ((size_t)(b*C2 + c)*HIN2)*HIN2;
  float s = 0.f;
  #pragma unroll
  for (int di=0; di<4; ++di){
    int y = i - 1 + di;
    if ((unsigned)y >= HIN2) continue;
    #pragma unroll
    for (int dj=0; dj<4; ++dj){
      int x = j - 1 + dj;
      if ((unsigned)x < HIN2) s += plane[y*HIN2 + x];
    }
  }
  embB[((size_t)((b*HO2 + i)*HO2 + j))*CC + c] = f2bf(s * (1.f/16.f));
}

__global__ void k_avgpool3(const float* __restrict__ in, float* __restrict__ f3p){
  int t = blockIdx.x*256 + threadIdx.x;
  if (t >= NB*HO3*HO3*C3) return;
  int c = t % C3; int r = t / C3;
  int j = r % HO3; r /= HO3;
  int i = r % HO3; int b = r / HO3;
  const float* plane = in + ((size_t)(b*C3 + c)*HIN3)*HIN3;
  float s = 0.f;
  #pragma unroll
  for (int di=0; di<4; ++di){
    int y = i - 1 + di;
    if ((unsigned)y >= HIN3) continue;
    #pragma unroll
    for (int dj=0; dj<4; ++dj){
      int x = j - 1 + dj;
      if ((unsigned)x < HIN3) s += plane[y*HIN3 + x];
    }
  }
  f3p[((size_t)((b*HO3 + i)*HO3 + j))*C3 + c] = s * (1.f/16.f);
}

// ---------------- bilinear 13x13 -> 27x27 (half-pixel, clamp), write bf16 ----------------
__global__ void k_upsample3(const float* __restrict__ f3p, ushort* __restrict__ embB){
  int t = blockIdx.x*256 + threadIdx.x;
  if (t >= NB*HO2*HO2*C3) return;
  int c = t % C3; int r = t / C3;
  int ox = r % HO2; r /= HO2;
  int oy = r % HO2; int b = r / HO2;
  float fy = (oy + 0.5f) * (13.f/27.f) - 0.5f;
  float fx = (ox + 0.5f) * (13.f/27.f) - 0.5f;
  int y0 = (int)floorf(fy); float wy = fy - (float)y0;
  int x0 = (int)floorf(fx); float wx = fx - (float)x0;
  int y0c = min(max(y0,0), HO3-1), y1c = min(max(y0+1,0), HO3-1);
  int x0c = min(max(x0,0), HO3-1), x1c = min(max(x0+1,0), HO3-1);
  const float* base = f3p + (size_t)(b*HO3*HO3)*C3;
  float v00 = base[(size_t)(y0c*HO3 + x0c)*C3 + c];
  float v01 = base[(size_t)(y0c*HO3 + x1c)*C3 + c];
  float v10 = base[(size_t)(y1c*HO3 + x0c)*C3 + c];
  float v11 = base[(size_t)(y1c*HO3 + x1c)*C3 + c];
  float v = (1.f-wy)*((1.f-wx)*v00 + wx*v01) + wy*((1.f-wx)*v10 + wx*v11);
  embB[((size_t)((b*HO2 + oy)*HO2 + ox))*CC + C2 + c] = f2bf(v);
}

// ---------------- fused bank fp32->bf16 convert + row sum of squares ----------------
__global__ void k_bank_prep(const float* __restrict__ bank, ushort* __restrict__ bankB,
                            float* __restrict__ y2){
  int wave = threadIdx.x >> 6, lane = threadIdx.x & 63;
  int r = blockIdx.x*4 + wave;
  if (r >= NM) return;
  const float4* p = (const float4*)(bank + (size_t)r*CC);
  ushort4* q = (ushort4*)(bankB + (size_t)r*CC);
  float s = 0.f;
  #pragma unroll
  for (int it=0; it<6; ++it){
    float4 v = p[it*64 + lane];
    s += v.x*v.x + v.y*v.y + v.z*v.z + v.w*v.w;
    ushort4 o; o.x = f2bf(v.x); o.y = f2bf(v.y); o.z = f2bf(v.z); o.w = f2bf(v.w);
    q[it*64 + lane] = o;
  }
  s = warp_sum(s);
  if (lane==0) y2[r] = s;
}

__global__ void k_rowsumsq_bf(const ushort* __restrict__ src, float* __restrict__ dst, int rows){
  int wave = threadIdx.x >> 6;
  int lane = threadIdx.x & 63;
  int r = blockIdx.x*4 + wave;
  if (r >= rows) return;
  const uint4* p = (const uint4*)(src + (size_t)r*CC);
  float s = 0.f;
  #pragma unroll
  for (int it=0; it<3; ++it){
    uint4 v = p[it*64 + lane];
    u32 ws_[4] = {v.x, v.y, v.z, v.w};
    #pragma unroll
    for (int q=0;q<4;q++){
      float lo = __uint_as_float(ws_[q]<<16);
      float hi = __uint_as_float(ws_[q]&0xFFFF0000u);
      s += lo*lo + hi*hi;
    }
  }
  s = warp_sum(s);
  if (lane==0) dst[r] = s;
}

__global__ void k_init(u64* __restrict__ packed){
  int t = blockIdx.x*256 + threadIdx.x;
  if (t < NP) packed[t] = ~0ull;
}

// ---------------- fused bf16 MFMA distance GEMM + min/argmin ----------------
// 256x256 tile, BK=64, 8 waves (2Mx4N, per-wave 128x64), double-buffered LDS,
// 2-phase pipeline: stage(next) issued before compute(cur), one vmcnt(0)+barrier/tile.
__global__ __launch_bounds__(512, 2) void k_distmin_mfma(
    const ushort* __restrict__ A, const ushort* __restrict__ B,
    const float* __restrict__ x2, const float* __restrict__ y2,
    u64* __restrict__ packed)
{
  __shared__ ushort smem[4*BM*BK];   // [buf0A | buf0B | buf1A | buf1B], 32KB each = 128KB
  ushort* A0 = smem;
  ushort* B0 = smem + BM*BK;
  ushort* A1 = smem + 2*BM*BK;
  ushort* B1 = smem + 3*BM*BK;

  const int tid = threadIdx.x;
  const int w   = tid >> 6;          // wave 0..7
  const int l   = tid & 63;
  const int wr  = w >> 2;            // 0..1  (M: wr*128)
  const int wc  = w & 3;             // 0..3  (N: wc*64)
  const int ccol = l & 15;
  const int cgrp = l >> 4;

  // bijective XCD swizzle (m204): nwg=2875, q=359, r=3
  int orig = blockIdx.x;
  const int q8 = NWG/8, r8 = NWG%8;
  int xcd = orig & 7, sidx = orig >> 3;
  int wg = (xcd < r8 ? xcd*(q8+1) : r8*(q8+1) + (xcd-r8)*q8) + sidx;
  const int mb = wg % MB_CNT;        // M fastest: consecutive wgs share B-panel
  const int nb = wg / MB_CNT;
  const int m0 = mb * BM;
  const int n0 = nb * BN;

  // staging addresses: 32 chunks of 8 rows; wave w owns chunks w*4..w*4+3.
  // lane l: row-in-chunk = l>>3, 16B segment (l&7) of the 128B row.
  size_t aOff[4], bOff[4];
  u32 ldsOff[4];
  #pragma unroll
  for (int c=0;c<4;c++){
    int chunk = w*4 + c;
    int row = chunk*8 + (l>>3);
    int col = (l&7)*8;
    aOff[c] = (size_t)min(m0 + row, NP-1)*CC + col;
    bOff[c] = (size_t)(n0 + row)*CC + col;
    ldsOff[c] = chunk*1024 + l*16;   // bytes
  }

  // fragment LDS indices (ushort units)
  u32 aIdx[8], bIdx[4];
  #pragma unroll
  for (int mi=0;mi<8;mi++) aIdx[mi] = (u32)(wr*128 + mi*16 + ccol)*BK + cgrp*8;
  #pragma unroll
  for (int ni=0;ni<4;ni++) bIdx[ni] = (u32)(wc*64 + ni*16 + ccol)*BK + cgrp*8;

  f32x4 acc[8][4];
  #pragma unroll
  for (int mi=0;mi<8;mi++)
    #pragma unroll
    for (int ni=0;ni<4;ni++)
      acc[mi][ni] = (f32x4){0.f,0.f,0.f,0.f};

  // prologue: stage k-tile 0 into buf0
  #pragma unroll
  for (int c=0;c<4;c++){
    GLDS(A + aOff[c], (char*)A0 + ldsOff[c]);
    GLDS(B + bOff[c], (char*)B0 + ldsOff[c]);
  }
  __syncthreads();   // compiler drains vmcnt before s_barrier

  const ushort* curA = A0; const ushort* curB = B0;
  ushort* stA = A1; ushort* stB = B1;

  #pragma unroll 1
  for (int kt=0; kt<KT; ++kt){
    if (kt+1 < KT){
      const u32 kk = (u32)(kt+1)*BK;
      #pragma unroll
      for (int c=0;c<4;c++){
        GLDS(A + aOff[c] + kk, (char*)stA + ldsOff[c]);
        GLDS(B + bOff[c] + kk, (char*)stB + ldsOff[c]);
      }
    }
    #pragma unroll
    for (int ks=0; ks<2; ++ks){
      bf16x8 a_[8], b_[4];
      #pragma unroll
      for (int mi=0;mi<8;mi++) a_[mi] = *(const bf16x8*)&curA[aIdx[mi] + ks*32];
      #pragma unroll
      for (int ni=0;ni<4;ni++) b_[ni] = *(const bf16x8*)&curB[bIdx[ni] + ks*32];
      #pragma unroll
      for (int mi=0;mi<8;mi++)
        #pragma unroll
        for (int ni=0;ni<4;ni++)
          acc[mi][ni] = __builtin_amdgcn_mfma_f32_16x16x32_bf16(a_[mi], b_[ni], acc[mi][ni], 0, 0, 0);
    }
    __syncthreads();   // drains stage(kt+1), and fences readers before buffer swap
    const ushort* tA = curA; curA = stA; stA = (ushort*)tA;
    const ushort* tB = curB; curB = stB; stB = (ushort*)tB;
  }

  // epilogue: d2 = x2 + y2 - 2*dot ; min over this block's 256 columns, then atomicMin
  float xv[8][4];
  #pragma unroll
  for (int mi=0;mi<8;mi++)
    #pragma unroll
    for (int r=0;r<4;r++)
      xv[mi][r] = x2[min(m0 + wr*128 + mi*16 + cgrp*4 + r, NP-1)];

  u64 best[8][4];
  #pragma unroll
  for (int mi=0;mi<8;mi++)
    #pragma unroll
    for (int r=0;r<4;r++) best[mi][r] = ~0ull;

  #pragma unroll
  for (int ni=0;ni<4;ni++){
    const int n = n0 + wc*64 + ni*16 + ccol;
    const float yy = y2[n];
    #pragma unroll
    for (int mi=0;mi<8;mi++)
      #pragma unroll
      for (int r=0;r<4;r++){
        float d2 = fmaxf(xv[mi][r] + yy - 2.f*acc[mi][ni][r], 0.f);
        u64 pk = (((u64)__float_as_uint(d2))<<32) | (u32)n;
        if (pk < best[mi][r]) best[mi][r] = pk;
      }
  }

  #pragma unroll
  for (int mi=0;mi<8;mi++)
    #pragma unroll
    for (int r=0;r<4;r++){
      u64 pk = best[mi][r];
      #pragma unroll
      for (int md=1; md<16; md<<=1){
        u64 o = __shfl_xor(pk, md);
        if (o < pk) pk = o;
      }
      const int row = m0 + wr*128 + mi*16 + cgrp*4 + r;
      if (ccol==0 && row < NP) atomicMin(&packed[row], pk);
    }
}

__global__ void k_unpack(const u64* __restrict__ packed, float* __restrict__ patch_d, int* __restrict__ loc){
  int t = blockIdx.x*256 + threadIdx.x;
  if (t < NP){
    u64 v = packed[t];
    patch_d[t] = sqrtf(__uint_as_float((u32)(v>>32)));
    loc[t] = (int)(v & 0xffffffffu);
  }
}

// ---------------- per-batch argmax of patch scores ----------------
__global__ void k_argmax(const float* __restrict__ patch_d, const int* __restrict__ loc,
                         int* __restrict__ sel_mp, float* __restrict__ sel_score, int* __restrict__ sel_nn){
  int b = blockIdx.x;
  int tid = threadIdx.x;
  __shared__ u64 red[4];
  u64 best = 0;
  for (int p = tid; p < HO2*HO2; p += 256){
    float v = patch_d[b*HO2*HO2 + p];
    u64 pk = (((u64)__float_as_uint(v))<<32) | (u32)(HO2*HO2 - p);  // tie -> smaller p wins on max
    if (pk > best) best = pk;
  }
  int lane = tid & 63, w = tid >> 6;
  #pragma unroll
  for (int d=32; d; d>>=1){ u64 o = __shfl_down(best, d); if (o > best) best = o; }
  if (lane==0) red[w] = best;
  __syncthreads();
  if (tid==0){
    u64 bb = red[0];
    for (int q=1;q<4;q++) if (red[q] > bb) bb = red[q];
    int p = HO2*HO2 - (int)(bb & 0xffffffffu);
    sel_mp[b] = p;
    sel_score[b] = __uint_as_float((u32)(bb>>32));
    sel_nn[b] = loc[b*HO2*HO2 + p];
  }
}

// ---------------- d2(nn_sample[b], bank[m]) for all b,m (fp32) ----------------
__global__ __launch_bounds__(256) void k_dbank(const float* __restrict__ bank, const float* __restrict__ y2,
    const int* __restrict__ sel_nn, float* __restrict__ d_bank){
  int wave = threadIdx.x >> 6, lane = threadIdx.x & 63;
  int m = blockIdx.x*4 + wave;
  if (m >= NM) return;
  int nn[NB];
  #pragma unroll
  for (int b=0;b<NB;b++) nn[b] = sel_nn[b];
  const float4* pm = (const float4*)(bank + (size_t)m*CC);
  float acc[NB];
  #pragma unroll
  for (int b=0;b<NB;b++) acc[b] = 0.f;
  for (int it=0; it<6; ++it){
    float4 v = pm[it*64 + lane];
    #pragma unroll
    for (int b=0;b<NB;b++){
      const float4* pn = (const float4*)(bank + (size_t)nn[b]*CC);
      float4 u = pn[it*64 + lane];
      acc[b] += v.x*u.x + v.y*u.y + v.z*u.z + v.w*u.w;
    }
  }
  #pragma unroll
  for (int b=0;b<NB;b++){
    float s = warp_sum(acc[b]);
    if (lane==0) d_bank[(size_t)b*NM + m] = fmaxf(y2[nn[b]] + y2[m] - 2.f*s, 0.f);
  }
}

// ---------------- single-pass top-9 + anomaly score ----------------
__global__ __launch_bounds__(256) void k_score(const float* __restrict__ d_bank, const float* __restrict__ bank,
    const ushort* __restrict__ embB, const float* __restrict__ x2, const float* __restrict__ y2,
    const int* __restrict__ sel_mp, const float* __restrict__ sel_score, float* __restrict__ out_score){
  int b = blockIdx.x, tid = threadIdx.x;
  __shared__ u64 cand[256*NKNN];
  __shared__ int sel[NKNN];
  __shared__ u64 red[4];
  __shared__ u64 gbest_s;
  __shared__ float fred[4];
  __shared__ float sumexp_s;

  // per-thread sorted top-9 of its strided slice, kept in LDS (dynamic idx -> LDS not scratch)
  #pragma unroll
  for (int q=0;q<NKNN;q++) cand[tid*NKNN+q] = ~0ull;
  for (int m = tid; m < NM; m += 256){
    float v = d_bank[(size_t)b*NM + m];
    u64 pk = (((u64)__float_as_uint(v))<<32) | (u32)m;
    if (pk < cand[tid*NKNN + NKNN-1]){
      cand[tid*NKNN + NKNN-1] = pk;
      for (int q=NKNN-1; q>0 && cand[tid*NKNN+q] < cand[tid*NKNN+q-1]; --q){
        u64 t = cand[tid*NKNN+q]; cand[tid*NKNN+q] = cand[tid*NKNN+q-1]; cand[tid*NKNN+q-1] = t;
      }
    }
  }
  __syncthreads();
  // 9 rounds of block-wide min over the 2304 candidates
  int lane = tid & 63, w = tid >> 6;
  for (int k=0;k<NKNN;++k){
    u64 mybest = ~0ull;
    #pragma unroll
    for (int q=0;q<NKNN;q++){ u64 v = cand[tid*NKNN+q]; if (v < mybest) mybest = v; }
    u64 rb = mybest;
    #pragma unroll
    for (int d=32; d; d>>=1){ u64 o = __shfl_down(rb, d); if (o < rb) rb = o; }
    if (lane==0) red[w] = rb;
    __syncthreads();
    if (tid==0){
      u64 bb = red[0];
      for (int q=1;q<4;q++) if (red[q] < bb) bb = red[q];
      gbest_s = bb;
      sel[k] = (int)(bb & 0xffffffffu);
    }
    __syncthreads();
    u64 gb = gbest_s;
    #pragma unroll
    for (int q=0;q<NKNN;q++) if (cand[tid*NKNN+q] == gb) cand[tid*NKNN+q] = ~0ull;
    __syncthreads();
  }

  int mp = sel_mp[b];
  const ushort* fv = embB + (size_t)(b*HO2*HO2 + mp)*CC;
  float fx2 = x2[b*HO2*HO2 + mp];
  if (tid==0) sumexp_s = 0.f;
  __syncthreads();
  for (int k=0;k<NKNN;++k){
    const float* sv = bank + (size_t)sel[k]*CC;
    float part = 0.f;
    for (int i = tid; i < CC; i += 256) part += bf2f(fv[i])*sv[i];
    part = warp_sum(part);
    if (lane==0) fred[w] = part;
    __syncthreads();
    if (tid==0){
      float dot = fred[0]+fred[1]+fred[2]+fred[3];
      float d2 = fmaxf(fx2 + y2[sel[k]] - 2.f*dot, 0.f);
      sumexp_s += expf(sqrtf(d2));
    }
    __syncthreads();
  }
  if (tid==0){
    float s = sel_score[b];
    out_score[b] = (1.f - expf(s)/sumexp_s) * s;
  }
}

// ---------------- anomaly map: bilinear 27 -> 224, then separable gaussian ----------------
__global__ void k_amap_bilinear(const float* __restrict__ patch_d, float* __restrict__ amap){
  int t = blockIdx.x*256 + threadIdx.x;
  if (t >= AMAP_N) return;
  int x = t % OH; int r = t / OH;
  int y = r % OH; int b = r / OH;
  float fy = (y + 0.5f) * (27.f/224.f) - 0.5f;
  float fx = (x + 0.5f) * (27.f/224.f) - 0.5f;
  int y0 = (int)floorf(fy); float wy = fy - (float)y0;
  int x0 = (int)floorf(fx); float wx = fx - (float)x0;
  int y0c = min(max(y0,0),HO2-1), y1c = min(max(y0+1,0),HO2-1);
  int x0c = min(max(x0,0),HO2-1), x1c = min(max(x0+1,0),HO2-1);
  const float* p = patch_d + b*HO2*HO2;
  float v = (1.f-wy)*((1.f-wx)*p[y0c*HO2+x0c] + wx*p[y0c*HO2+x1c])
          + wy*((1.f-wx)*p[y1c*HO2+x0c] + wx*p[y1c*HO2+x1c]);
  amap[t] = v;
}

__global__ void k_blur_h(const float* __restrict__ in, float* __restrict__ out, GW gw){
  int t = blockIdx.x*256 + threadIdx.x;
  if (t >= AMAP_N) return;
  int x = t % OH; int rest = t / OH;
  const float* row = in + (size_t)rest*OH;
  float s = 0.f;
  #pragma unroll
  for (int k=0;k<33;++k){
    int xx = x + k - 16;
    xx = (xx < 0) ? -xx : xx;
    xx = (xx > OH-1) ? (2*(OH-1) - xx) : xx;
    s += gw.w[k]*row[xx];
  }
  out[t] = s;
}

__global__ void k_blur_v(const float* __restrict__ in, float* __restrict__ out, GW gw){
  int t = blockIdx.x*256 + threadIdx.x;
  if (t >= AMAP_N) return;
  int x = t % OH; int r = t / OH;
  int y = r % OH; int b = r / OH;
  const float* img = in + (size_t)b*OH*OH;
  float s = 0.f;
  #pragma unroll
  for (int k=0;k<33;++k){
    int yy = y + k - 16;
    yy = (yy < 0) ? -yy : yy;
    yy = (yy > OH-1) ? (2*(OH-1) - yy) : yy;
    s += gw.w[k]*img[(size_t)yy*OH + x];
  }
  out[t] = s;
}

extern "C" void kernel_launch(void* const* d_in, const int* in_sizes, int n_in,
                              void* d_out, int out_size, void* d_ws, size_t ws_size,
                              hipStream_t stream){
  const float* f2   = (const float*)d_in[0];
  const float* f3   = (const float*)d_in[1];
  const float* bank = (const float*)d_in[2];
  float* out = (float*)d_out;

  char* ws = (char*)d_ws;
  size_t off = 0;
  auto alloc = [&](size_t bytes)->char*{ char* p = ws + off; off += (bytes + 255) & ~(size_t)255; return p; };
  ushort* embB    = (ushort*)alloc((size_t)NP*CC*2);
  ushort* bankB   = (ushort*)alloc((size_t)NM*CC*2);
  float* f3p      = (float*)alloc((size_t)NB*HO3*HO3*C3*4);
  float* y2       = (float*)alloc((size_t)NM*4);
  float* x2       = (float*)alloc((size_t)NP*4);
  u64*   packed   = (u64*)  alloc((size_t)NP*8);
  float* patch_d  = (float*)alloc((size_t)NP*4);
  int*   loc      = (int*)  alloc((size_t)NP*4);
  float* d_bank   = (float*)alloc((size_t)NB*NM*4);
  int*   sel_mp   = (int*)  alloc(NB*4);
  float* sel_scr  = (float*)alloc(NB*4);
  int*   sel_nn   = (int*)  alloc(NB*4);
  float* amap1    = (float*)alloc((size_t)AMAP_N*4);
  float* amap2    = (float*)alloc((size_t)AMAP_N*4);

  GW gw;
  { float s=0.f; for(int i=0;i<33;i++){ float xx=(float)i-16.f; gw.w[i]=expf(-0.5f*(xx/4.f)*(xx/4.f)); s+=gw.w[i]; }
    for(int i=0;i<33;i++) gw.w[i]/=s; }

  k_avgpool2<<<(NB*HO2*HO2*C2+255)/256,256,0,stream>>>(f2, embB);
  k_avgpool3<<<(NB*HO3*HO3*C3+255)/256,256,0,stream>>>(f3, f3p);
  k_upsample3<<<(NB*HO2*HO2*C3+255)/256,256,0,stream>>>(f3p, embB);
  k_bank_prep<<<(NM+3)/4,256,0,stream>>>(bank, bankB, y2);
  k_rowsumsq_bf<<<(NP+3)/4,256,0,stream>>>(embB, x2, NP);
  k_init<<<(NP+255)/256,256,0,stream>>>(packed);
  k_distmin_mfma<<<NWG,512,0,stream>>>(embB, bankB, x2, y2, packed);
  k_unpack<<<(NP+255)/256,256,0,stream>>>(packed, patch_d, loc);
  k_argmax<<<NB,256,0,stream>>>(patch_d, loc, sel_mp, sel_scr, sel_nn);
  k_dbank<<<(NM+3)/4,256,0,stream>>>(bank, y2, sel_nn, d_bank);
  k_score<<<NB,256,0,stream>>>(d_bank, bank, embB, x2, y2, sel_mp, sel_scr, out + AMAP_N);
  k_amap_bilinear<<<(AMAP_N+255)/256,256,0,stream>>>(patch_d, amap1);
  k_blur_h<<<(AMAP_N+255)/256,256,0,stream>>>(amap1, amap2, gw);
  k_blur_v<<<(AMAP_N+255)/256,256,0,stream>>>(amap2, out, gw);
}

// Round 4
// 1110.842 us; speedup vs baseline: 8.3823x; 1.0728x over previous
//
#include <hip/hip_runtime.h>
#include <math.h>

#define NB 8
#define C2 512
#define C3 1024
#define HIN2 28
#define HIN3 14
#define HO2 27
#define HO3 13
#define CC 1536
#define NP (NB*HO2*HO2)   /* 5832 */
#define NM 32000
#define NKNN 9
#define OH 224
#define AMAP_N (NB*OH*OH) /* 401408 */

/* 256x256 tile GEMM geometry */
#define BM 256
#define BN 256
#define BK 64
#define KT (CC/BK)        /* 24 */
#define MB_CNT ((NP+BM-1)/BM)   /* 23 */
#define NB_CNT (NM/BN)          /* 125 */
#define NWG (MB_CNT*NB_CNT)     /* 2875 */

typedef unsigned long long u64;
typedef unsigned int u32;
typedef __attribute__((ext_vector_type(8))) short bf16x8;
typedef __attribute__((ext_vector_type(4))) float f32x4;

struct GW { float w[33]; };

__device__ __forceinline__ float warp_sum(float v){
  #pragma unroll
  for (int off=32; off; off>>=1) v += __shfl_down(v, off);
  return v;
}

__device__ __forceinline__ ushort f2bf(float f){
  u32 u = __float_as_uint(f);
  u32 r = (u + 0x7FFFu + ((u>>16)&1u)) >> 16;
  return (ushort)r;
}
__device__ __forceinline__ float bf2f(ushort b){
  return __uint_as_float(((u32)b)<<16);
}

#define GLDS(g, l) __builtin_amdgcn_global_load_lds((const __attribute__((address_space(1))) void*)(g), (__attribute__((address_space(3))) void*)(l), 16, 0, 0)
#define WAITVM8() asm volatile("s_waitcnt vmcnt(8)" ::: "memory")
#define WAITVM0() asm volatile("s_waitcnt vmcnt(0)" ::: "memory")
#define WAITLGKM0() asm volatile("s_waitcnt lgkmcnt(0)" ::: "memory")
__device__ __forceinline__ void bar_raw(){
  asm volatile("" ::: "memory");
  __builtin_amdgcn_s_barrier();
  asm volatile("" ::: "memory");
}

// ---------------- avg pool k=4,s=1,p=1, write bf16 embedding ----------------
__global__ void k_avgpool2(const float* __restrict__ in, ushort* __restrict__ embB){
  int t = blockIdx.x*256 + threadIdx.x;
  if (t >= NB*HO2*HO2*C2) return;
  int c = t % C2; int r = t / C2;
  int j = r % HO2; r /= HO2;
  int i = r % HO2; int b = r / HO2;
  const float* plane = in + ((size_t)(b*C2 + c)*HIN2)*HIN2;
  float s = 0.f;
  #pragma unroll
  for (int di=0; di<4; ++di){
    int y = i - 1 + di;
    if ((unsigned)y >= HIN2) continue;
    #pragma unroll
    for (int dj=0; dj<4; ++dj){
      int x = j - 1 + dj;
      if ((unsigned)x < HIN2) s += plane[y*HIN2 + x];
    }
  }
  embB[((size_t)((b*HO2 + i)*HO2 + j))*CC + c] = f2bf(s * (1.f/16.f));
}

__global__ void k_avgpool3(const float* __restrict__ in, float* __restrict__ f3p){
  int t = blockIdx.x*256 + threadIdx.x;
  if (t >= NB*HO3*HO3*C3) return;
  int c = t % C3; int r = t / C3;
  int j = r % HO3; r /= HO3;
  int i = r % HO3; int b = r / HO3;
  const float* plane = in + ((size_t)(b*C3 + c)*HIN3)*HIN3;
  float s = 0.f;
  #pragma unroll
  for (int di=0; di<4; ++di){
    int y = i - 1 + di;
    if ((unsigned)y >= HIN3) continue;
    #pragma unroll
    for (int dj=0; dj<4; ++dj){
      int x = j - 1 + dj;
      if ((unsigned)x < HIN3) s += plane[y*HIN3 + x];
    }
  }
  f3p[((size_t)((b*HO3 + i)*HO3 + j))*C3 + c] = s * (1.f/16.f);
}

// ---------------- bilinear 13x13 -> 27x27 (half-pixel, clamp), write bf16 ----------------
__global__ void k_upsample3(const float* __restrict__ f3p, ushort* __restrict__ embB){
  int t = blockIdx.x*256 + threadIdx.x;
  if (t >= NB*HO2*HO2*C3) return;
  int c = t % C3; int r = t / C3;
  int ox = r % HO2; r /= HO2;
  int oy = r % HO2; int b = r / HO2;
  float fy = (oy + 0.5f) * (13.f/27.f) - 0.5f;
  float fx = (ox + 0.5f) * (13.f/27.f) - 0.5f;
  int y0 = (int)floorf(fy); float wy = fy - (float)y0;
  int x0 = (int)floorf(fx); float wx = fx - (float)x0;
  int y0c = min(max(y0,0), HO3-1), y1c = min(max(y0+1,0), HO3-1);
  int x0c = min(max(x0,0), HO3-1), x1c = min(max(x0+1,0), HO3-1);
  const float* base = f3p + (size_t)(b*HO3*HO3)*C3;
  float v00 = base[(size_t)(y0c*HO3 + x0c)*C3 + c];
  float v01 = base[(size_t)(y0c*HO3 + x1c)*C3 + c];
  float v10 = base[(size_t)(y1c*HO3 + x0c)*C3 + c];
  float v11 = base[(size_t)(y1c*HO3 + x1c)*C3 + c];
  float v = (1.f-wy)*((1.f-wx)*v00 + wx*v01) + wy*((1.f-wx)*v10 + wx*v11);
  embB[((size_t)((b*HO2 + oy)*HO2 + ox))*CC + C2 + c] = f2bf(v);
}

// ---------------- fused bank fp32->bf16 convert + row sum of squares ----------------
__global__ void k_bank_prep(const float* __restrict__ bank, ushort* __restrict__ bankB,
                            float* __restrict__ y2){
  int wave = threadIdx.x >> 6, lane = threadIdx.x & 63;
  int r = blockIdx.x*4 + wave;
  if (r >= NM) return;
  const float4* p = (const float4*)(bank + (size_t)r*CC);
  ushort4* q = (ushort4*)(bankB + (size_t)r*CC);
  float s = 0.f;
  #pragma unroll
  for (int it=0; it<6; ++it){
    float4 v = p[it*64 + lane];
    s += v.x*v.x + v.y*v.y + v.z*v.z + v.w*v.w;
    ushort4 o; o.x = f2bf(v.x); o.y = f2bf(v.y); o.z = f2bf(v.z); o.w = f2bf(v.w);
    q[it*64 + lane] = o;
  }
  s = warp_sum(s);
  if (lane==0) y2[r] = s;
}

__global__ void k_rowsumsq_bf(const ushort* __restrict__ src, float* __restrict__ dst, int rows){
  int wave = threadIdx.x >> 6;
  int lane = threadIdx.x & 63;
  int r = blockIdx.x*4 + wave;
  if (r >= rows) return;
  const uint4* p = (const uint4*)(src + (size_t)r*CC);
  float s = 0.f;
  #pragma unroll
  for (int it=0; it<3; ++it){
    uint4 v = p[it*64 + lane];
    u32 ws_[4] = {v.x, v.y, v.z, v.w};
    #pragma unroll
    for (int q=0;q<4;q++){
      float lo = __uint_as_float(ws_[q]<<16);
      float hi = __uint_as_float(ws_[q]&0xFFFF0000u);
      s += lo*lo + hi*hi;
    }
  }
  s = warp_sum(s);
  if (lane==0) dst[r] = s;
}

__global__ void k_init(u64* __restrict__ packed){
  int t = blockIdx.x*256 + threadIdx.x;
  if (t < NP) packed[t] = ~0ull;
}

// ---------------- fused bf16 MFMA distance GEMM + min/argmin ----------------
// 256x256 tile, BK=64, 8 waves (2Mx4N), double-buffered LDS.
// T4: raw s_barrier + counted vmcnt(8) -- next-tile global_load_lds stays in
//     flight across the barrier; only the current tile's (oldest 8) must land.
// T2: XOR-swizzled LDS layout via pre-swizzled GLOBAL source (rule #21):
//     LDS[row][seg] holds global (row, seg^(row&7)); chunk rows are 8-aligned
//     so row&7 == l>>3 and source col = ((l&7)^(l>>3))*8 (lane-only).
//     Fragment reads XOR the same involution -> 2-way banked (free).
__global__ __launch_bounds__(512, 2) void k_distmin_mfma(
    const ushort* __restrict__ A, const ushort* __restrict__ B,
    const float* __restrict__ x2, const float* __restrict__ y2,
    u64* __restrict__ packed)
{
  __shared__ ushort smem[4*BM*BK];   // [buf0A | buf0B | buf1A | buf1B] = 128KB
  ushort* A0 = smem;
  ushort* B0 = smem + BM*BK;
  ushort* A1 = smem + 2*BM*BK;
  ushort* B1 = smem + 3*BM*BK;

  const int tid = threadIdx.x;
  const int w   = tid >> 6;          // wave 0..7
  const int l   = tid & 63;
  const int wr  = w >> 2;            // 0..1  (M: wr*128)
  const int wc  = w & 3;             // 0..3  (N: wc*64)
  const int ccol = l & 15;
  const int cgrp = l >> 4;

  // bijective XCD swizzle (m204): nwg=2875
  int orig = blockIdx.x;
  const int q8 = NWG/8, r8 = NWG%8;
  int xcd = orig & 7, sidx = orig >> 3;
  int wg = (xcd < r8 ? xcd*(q8+1) : r8*(q8+1) + (xcd-r8)*q8) + sidx;
  const int mb = wg % MB_CNT;        // M fastest: consecutive wgs share B-panel
  const int nb = wg / MB_CNT;
  const int m0 = mb * BM;
  const int n0 = nb * BN;

  // staging: 32 chunks of 8 rows; wave w owns chunks w*4..w*4+3.
  // lane l: row-in-chunk = l>>3; swizzled source segment = (l&7)^(l>>3).
  const int scol = (((l&7) ^ (l>>3)) * 8);
  size_t aOff[4], bOff[4];
  u32 ldsOff[4];
  #pragma unroll
  for (int c=0;c<4;c++){
    int chunk = w*4 + c;
    int row = chunk*8 + (l>>3);
    aOff[c] = (size_t)min(m0 + row, NP-1)*CC + scol;
    bOff[c] = (size_t)(n0 + row)*CC + scol;
    ldsOff[c] = chunk*1024 + l*16;   // bytes; wave-uniform base + lane*16
  }

  // fragment read indices (ushort units): row*64 + ((ks*4+cgrp)^(ccol&7))*8
  // and ((4+cgrp)^x)*8 == ((cgrp^x)*8) ^ 32  ->  o(ks) = o0 ^ (ks<<5)
  const u32 o0 = (u32)((cgrp ^ (ccol & 7)) * 8);
  u32 aRow[8], bRow[4];
  #pragma unroll
  for (int mi=0;mi<8;mi++) aRow[mi] = (u32)(wr*128 + mi*16 + ccol)*BK;
  #pragma unroll
  for (int ni=0;ni<4;ni++) bRow[ni] = (u32)(wc*64 + ni*16 + ccol)*BK;

  f32x4 acc[8][4];
  #pragma unroll
  for (int mi=0;mi<8;mi++)
    #pragma unroll
    for (int ni=0;ni<4;ni++)
      acc[mi][ni] = (f32x4){0.f,0.f,0.f,0.f};

  // prologue: stage k-tile 0 into buf0
  #pragma unroll
  for (int c=0;c<4;c++){
    GLDS(A + aOff[c], (char*)A0 + ldsOff[c]);
    GLDS(B + bOff[c], (char*)B0 + ldsOff[c]);
  }

  const ushort* curA = A0; const ushort* curB = B0;
  ushort* stA = A1; ushort* stB = B1;

  #pragma unroll 1
  for (int kt=0; kt<KT; ++kt){
    if (kt+1 < KT){
      const u32 kk = (u32)(kt+1)*BK;
      #pragma unroll
      for (int c=0;c<4;c++){
        GLDS(A + aOff[c] + kk, (char*)stA + ldsOff[c]);
        GLDS(B + bOff[c] + kk, (char*)stB + ldsOff[c]);
      }
      WAITVM8();         // oldest 8 (cur tile) done; next 8 stay in flight
    } else {
      WAITVM0();
    }
    bar_raw();           // all waves: cur tile resident

    #pragma unroll
    for (int ks=0; ks<2; ++ks){
      const u32 so = o0 ^ (u32)(ks<<5);
      bf16x8 a_[8], b_[4];
      #pragma unroll
      for (int mi=0;mi<8;mi++) a_[mi] = *(const bf16x8*)&curA[aRow[mi] + so];
      #pragma unroll
      for (int ni=0;ni<4;ni++) b_[ni] = *(const bf16x8*)&curB[bRow[ni] + so];
      __builtin_amdgcn_s_setprio(1);
      #pragma unroll
      for (int mi=0;mi<8;mi++)
        #pragma unroll
        for (int ni=0;ni<4;ni++)
          acc[mi][ni] = __builtin_amdgcn_mfma_f32_16x16x32_bf16(a_[mi], b_[ni], acc[mi][ni], 0, 0, 0);
      __builtin_amdgcn_s_setprio(0);
    }
    WAITLGKM0();                      // all my ds_reads landed
    __builtin_amdgcn_sched_barrier(0);
    bar_raw();                        // safe to overwrite cur next iter
    ushort* tA = (ushort*)curA; curA = stA; stA = tA;
    ushort* tB = (ushort*)curB; curB = stB; stB = tB;
  }

  // epilogue: d2 = x2 + y2 - 2*dot ; min over this block's 256 columns, then atomicMin
  float xv[8][4];
  #pragma unroll
  for (int mi=0;mi<8;mi++)
    #pragma unroll
    for (int r=0;r<4;r++)
      xv[mi][r] = x2[min(m0 + wr*128 + mi*16 + cgrp*4 + r, NP-1)];

  u64 best[8][4];
  #pragma unroll
  for (int mi=0;mi<8;mi++)
    #pragma unroll
    for (int r=0;r<4;r++) best[mi][r] = ~0ull;

  #pragma unroll
  for (int ni=0;ni<4;ni++){
    const int n = n0 + wc*64 + ni*16 + ccol;
    const float yy = y2[n];
    #pragma unroll
    for (int mi=0;mi<8;mi++)
      #pragma unroll
      for (int r=0;r<4;r++){
        float d2 = fmaxf(xv[mi][r] + yy - 2.f*acc[mi][ni][r], 0.f);
        u64 pk = (((u64)__float_as_uint(d2))<<32) | (u32)n;
        if (pk < best[mi][r]) best[mi][r] = pk;
      }
  }

  #pragma unroll
  for (int mi=0;mi<8;mi++)
    #pragma unroll
    for (int r=0;r<4;r++){
      u64 pk = best[mi][r];
      #pragma unroll
      for (int md=1; md<16; md<<=1){
        u64 o = __shfl_xor(pk, md);
        if (o < pk) pk = o;
      }
      const int row = m0 + wr*128 + mi*16 + cgrp*4 + r;
      if (ccol==0 && row < NP) atomicMin(&packed[row], pk);
    }
}

__global__ void k_unpack(const u64* __restrict__ packed, float* __restrict__ patch_d, int* __restrict__ loc){
  int t = blockIdx.x*256 + threadIdx.x;
  if (t < NP){
    u64 v = packed[t];
    patch_d[t] = sqrtf(__uint_as_float((u32)(v>>32)));
    loc[t] = (int)(v & 0xffffffffu);
  }
}

// ---------------- per-batch argmax of patch scores ----------------
__global__ void k_argmax(const float* __restrict__ patch_d, const int* __restrict__ loc,
                         int* __restrict__ sel_mp, float* __restrict__ sel_score, int* __restrict__ sel_nn){
  int b = blockIdx.x;
  int tid = threadIdx.x;
  __shared__ u64 red[4];
  u64 best = 0;
  for (int p = tid; p < HO2*HO2; p += 256){
    float v = patch_d[b*HO2*HO2 + p];
    u64 pk = (((u64)__float_as_uint(v))<<32) | (u32)(HO2*HO2 - p);  // tie -> smaller p wins on max
    if (pk > best) best = pk;
  }
  int lane = tid & 63, w = tid >> 6;
  #pragma unroll
  for (int d=32; d; d>>=1){ u64 o = __shfl_down(best, d); if (o > best) best = o; }
  if (lane==0) red[w] = best;
  __syncthreads();
  if (tid==0){
    u64 bb = red[0];
    for (int q=1;q<4;q++) if (red[q] > bb) bb = red[q];
    int p = HO2*HO2 - (int)(bb & 0xffffffffu);
    sel_mp[b] = p;
    sel_score[b] = __uint_as_float((u32)(bb>>32));
    sel_nn[b] = loc[b*HO2*HO2 + p];
  }
}

// ---------------- d2(nn_sample[b], bank[m]) for all b,m (bf16 bank) ----------------
__device__ __forceinline__ void bf8dec(uint4 v, float* f){
  u32 a[4] = {v.x, v.y, v.z, v.w};
  #pragma unroll
  for (int q=0;q<4;q++){
    f[2*q]   = __uint_as_float(a[q]<<16);
    f[2*q+1] = __uint_as_float(a[q]&0xFFFF0000u);
  }
}

__global__ __launch_bounds__(256) void k_dbank(const ushort* __restrict__ bankB, const float* __restrict__ y2,
    const int* __restrict__ sel_nn, float* __restrict__ d_bank){
  int wave = threadIdx.x >> 6, lane = threadIdx.x & 63;
  int m = blockIdx.x*4 + wave;
  if (m >= NM) return;
  int nn[NB];
  #pragma unroll
  for (int b=0;b<NB;b++) nn[b] = sel_nn[b];
  const uint4* pm = (const uint4*)(bankB + (size_t)m*CC);
  float acc[NB];
  #pragma unroll
  for (int b=0;b<NB;b++) acc[b] = 0.f;
  #pragma unroll
  for (int it=0; it<3; ++it){
    uint4 v = pm[it*64 + lane];
    float vf[8]; bf8dec(v, vf);
    #pragma unroll
    for (int b=0;b<NB;b++){
      uint4 u = ((const uint4*)(bankB + (size_t)nn[b]*CC))[it*64 + lane];
      float uf[8]; bf8dec(u, uf);
      #pragma unroll
      for (int q=0;q<8;q++) acc[b] += vf[q]*uf[q];
    }
  }
  #pragma unroll
  for (int b=0;b<NB;b++){
    float s = warp_sum(acc[b]);
    if (lane==0) d_bank[(size_t)b*NM + m] = fmaxf(y2[nn[b]] + y2[m] - 2.f*s, 0.f);
  }
}

// ---------------- single-pass top-9 + anomaly score ----------------
__global__ __launch_bounds__(256) void k_score(const float* __restrict__ d_bank, const float* __restrict__ bank,
    const ushort* __restrict__ embB, const float* __restrict__ x2, const float* __restrict__ y2,
    const int* __restrict__ sel_mp, const float* __restrict__ sel_score, float* __restrict__ out_score){
  int b = blockIdx.x, tid = threadIdx.x;
  __shared__ u64 cand[256*NKNN];
  __shared__ int sel[NKNN];
  __shared__ u64 red[4];
  __shared__ u64 gbest_s;
  __shared__ float fred[4];
  __shared__ float sumexp_s;

  #pragma unroll
  for (int q=0;q<NKNN;q++) cand[tid*NKNN+q] = ~0ull;
  for (int m = tid; m < NM; m += 256){
    float v = d_bank[(size_t)b*NM + m];
    u64 pk = (((u64)__float_as_uint(v))<<32) | (u32)m;
    if (pk < cand[tid*NKNN + NKNN-1]){
      cand[tid*NKNN + NKNN-1] = pk;
      for (int q=NKNN-1; q>0 && cand[tid*NKNN+q] < cand[tid*NKNN+q-1]; --q){
        u64 t = cand[tid*NKNN+q]; cand[tid*NKNN+q] = cand[tid*NKNN+q-1]; cand[tid*NKNN+q-1] = t;
      }
    }
  }
  __syncthreads();
  int lane = tid & 63, w = tid >> 6;
  for (int k=0;k<NKNN;++k){
    u64 mybest = ~0ull;
    #pragma unroll
    for (int q=0;q<NKNN;q++){ u64 v = cand[tid*NKNN+q]; if (v < mybest) mybest = v; }
    u64 rb = mybest;
    #pragma unroll
    for (int d=32; d; d>>=1){ u64 o = __shfl_down(rb, d); if (o < rb) rb = o; }
    if (lane==0) red[w] = rb;
    __syncthreads();
    if (tid==0){
      u64 bb = red[0];
      for (int q=1;q<4;q++) if (red[q] < bb) bb = red[q];
      gbest_s = bb;
      sel[k] = (int)(bb & 0xffffffffu);
    }
    __syncthreads();
    u64 gb = gbest_s;
    #pragma unroll
    for (int q=0;q<NKNN;q++) if (cand[tid*NKNN+q] == gb) cand[tid*NKNN+q] = ~0ull;
    __syncthreads();
  }

  int mp = sel_mp[b];
  const ushort* fv = embB + (size_t)(b*HO2*HO2 + mp)*CC;
  float fx2 = x2[b*HO2*HO2 + mp];
  if (tid==0) sumexp_s = 0.f;
  __syncthreads();
  for (int k=0;k<NKNN;++k){
    const float* sv = bank + (size_t)sel[k]*CC;
    float part = 0.f;
    for (int i = tid; i < CC; i += 256) part += bf2f(fv[i])*sv[i];
    part = warp_sum(part);
    if (lane==0) fred[w] = part;
    __syncthreads();
    if (tid==0){
      float dot = fred[0]+fred[1]+fred[2]+fred[3];
      float d2 = fmaxf(fx2 + y2[sel[k]] - 2.f*dot, 0.f);
      sumexp_s += expf(sqrtf(d2));
    }
    __syncthreads();
  }
  if (tid==0){
    float s = sel_score[b];
    out_score[b] = (1.f - expf(s)/sumexp_s) * s;
  }
}

// ---------------- anomaly map: bilinear 27 -> 224, then separable gaussian ----------------
__global__ void k_amap_bilinear(const float* __restrict__ patch_d, float* __restrict__ amap){
  int t = blockIdx.x*256 + threadIdx.x;
  if (t >= AMAP_N) return;
  int x = t % OH; int r = t / OH;
  int y = r % OH; int b = r / OH;
  float fy = (y + 0.5f) * (27.f/224.f) - 0.5f;
  float fx = (x + 0.5f) * (27.f/224.f) - 0.5f;
  int y0 = (int)floorf(fy); float wy = fy - (float)y0;
  int x0 = (int)floorf(fx); float wx = fx - (float)x0;
  int y0c = min(max(y0,0),HO2-1), y1c = min(max(y0+1,0),HO2-1);
  int x0c = min(max(x0,0),HO2-1), x1c = min(max(x0+1,0),HO2-1);
  const float* p = patch_d + b*HO2*HO2;
  float v = (1.f-wy)*((1.f-wx)*p[y0c*HO2+x0c] + wx*p[y0c*HO2+x1c])
          + wy*((1.f-wx)*p[y1c*HO2+x0c] + wx*p[y1c*HO2+x1c]);
  amap[t] = v;
}

__global__ void k_blur_h(const float* __restrict__ in, float* __restrict__ out, GW gw){
  int t = blockIdx.x*256 + threadIdx.x;
  if (t >= AMAP_N) return;
  int x = t % OH; int rest = t / OH;
  const float* row = in + (size_t)rest*OH;
  float s = 0.f;
  #pragma unroll
  for (int k=0;k<33;++k){
    int xx = x + k - 16;
    xx = (xx < 0) ? -xx : xx;
    xx = (xx > OH-1) ? (2*(OH-1) - xx) : xx;
    s += gw.w[k]*row[xx];
  }
  out[t] = s;
}

__global__ void k_blur_v(const float* __restrict__ in, float* __restrict__ out, GW gw){
  int t = blockIdx.x*256 + threadIdx.x;
  if (t >= AMAP_N) return;
  int x = t % OH; int r = t / OH;
  int y = r % OH; int b = r / OH;
  const float* img = in + (size_t)b*OH*OH;
  float s = 0.f;
  #pragma unroll
  for (int k=0;k<33;++k){
    int yy = y + k - 16;
    yy = (yy < 0) ? -yy : yy;
    yy = (yy > OH-1) ? (2*(OH-1) - yy) : yy;
    s += gw.w[k]*img[(size_t)yy*OH + x];
  }
  out[t] = s;
}

extern "C" void kernel_launch(void* const* d_in, const int* in_sizes, int n_in,
                              void* d_out, int out_size, void* d_ws, size_t ws_size,
                              hipStream_t stream){
  const float* f2   = (const float*)d_in[0];
  const float* f3   = (const float*)d_in[1];
  const float* bank = (const float*)d_in[2];
  float* out = (float*)d_out;

  char* ws = (char*)d_ws;
  size_t off = 0;
  auto alloc = [&](size_t bytes)->char*{ char* p = ws + off; off += (bytes + 255) & ~(size_t)255; return p; };
  ushort* embB    = (ushort*)alloc((size_t)NP*CC*2);
  ushort* bankB   = (ushort*)alloc((size_t)NM*CC*2);
  float* f3p      = (float*)alloc((size_t)NB*HO3*HO3*C3*4);
  float* y2       = (float*)alloc((size_t)NM*4);
  float* x2       = (float*)alloc((size_t)NP*4);
  u64*   packed   = (u64*)  alloc((size_t)NP*8);
  float* patch_d  = (float*)alloc((size_t)NP*4);
  int*   loc      = (int*)  alloc((size_t)NP*4);
  float* d_bank   = (float*)alloc((size_t)NB*NM*4);
  int*   sel_mp   = (int*)  alloc(NB*4);
  float* sel_scr  = (float*)alloc(NB*4);
  int*   sel_nn   = (int*)  alloc(NB*4);
  float* amap1    = (float*)alloc((size_t)AMAP_N*4);
  float* amap2    = (float*)alloc((size_t)AMAP_N*4);

  GW gw;
  { float s=0.f; for(int i=0;i<33;i++){ float xx=(float)i-16.f; gw.w[i]=expf(-0.5f*(xx/4.f)*(xx/4.f)); s+=gw.w[i]; }
    for(int i=0;i<33;i++) gw.w[i]/=s; }

  k_avgpool2<<<(NB*HO2*HO2*C2+255)/256,256,0,stream>>>(f2, embB);
  k_avgpool3<<<(NB*HO3*HO3*C3+255)/256,256,0,stream>>>(f3, f3p);
  k_upsample3<<<(NB*HO2*HO2*C3+255)/256,256,0,stream>>>(f3p, embB);
  k_bank_prep<<<(NM+3)/4,256,0,stream>>>(bank, bankB, y2);
  k_rowsumsq_bf<<<(NP+3)/4,256,0,stream>>>(embB, x2, NP);
  k_init<<<(NP+255)/256,256,0,stream>>>(packed);
  k_distmin_mfma<<<NWG,512,0,stream>>>(embB, bankB, x2, y2, packed);
  k_unpack<<<(NP+255)/256,256,0,stream>>>(packed, patch_d, loc);
  k_argmax<<<NB,256,0,stream>>>(patch_d, loc, sel_mp, sel_scr, sel_nn);
  k_dbank<<<(NM+3)/4,256,0,stream>>>(bankB, y2, sel_nn, d_bank);
  k_score<<<NB,256,0,stream>>>(d_bank, bank, embB, x2, y2, sel_mp, sel_scr, out + AMAP_N);
  k_amap_bilinear<<<(AMAP_N+255)/256,256,0,stream>>>(patch_d, amap1);
  k_blur_h<<<(AMAP_N+255)/256,256,0,stream>>>(amap1, amap2, gw);
  k_blur_v<<<(AMAP_N+255)/256,256,0,stream>>>(amap2, out, gw);
}

// Round 5
// 1041.402 us; speedup vs baseline: 8.9412x; 1.0667x over previous
//
#include <hip/hip_runtime.h>
#include <math.h>

#define NB 8
#define C2 512
#define C3 1024
#define HIN2 28
#define HIN3 14
#define HO2 27
#define HO3 13
#define CC 1536
#define NP (NB*HO2*HO2)   /* 5832 */
#define NM 32000
#define NKNN 9
#define OH 224
#define AMAP_N (NB*OH*OH) /* 401408 */

/* 256x256 tile GEMM geometry */
#define BM 256
#define BN 256
#define BK 64
#define KT (CC/BK)        /* 24 */
#define MB_CNT ((NP+BM-1)/BM)   /* 23 */
#define NB_CNT (NM/BN)          /* 125 */
#define NWG (MB_CNT*NB_CNT)     /* 2875 */

typedef unsigned long long u64;
typedef unsigned int u32;
typedef __attribute__((ext_vector_type(8))) short bf16x8;
typedef __attribute__((ext_vector_type(4))) float f32x4;

struct GW { float w[33]; };

__device__ __forceinline__ float warp_sum(float v){
  #pragma unroll
  for (int off=32; off; off>>=1) v += __shfl_down(v, off);
  return v;
}

__device__ __forceinline__ ushort f2bf(float f){
  u32 u = __float_as_uint(f);
  u32 r = (u + 0x7FFFu + ((u>>16)&1u)) >> 16;
  return (ushort)r;
}
__device__ __forceinline__ float bf2f(ushort b){
  return __uint_as_float(((u32)b)<<16);
}

#define GLDS(g, l) __builtin_amdgcn_global_load_lds((const __attribute__((address_space(1))) void*)(g), (__attribute__((address_space(3))) void*)(l), 16, 0, 0)
#define WAITVM2() asm volatile("s_waitcnt vmcnt(2)" ::: "memory")
#define WAITVM0() asm volatile("s_waitcnt vmcnt(0)" ::: "memory")
__device__ __forceinline__ void bar_raw(){
  asm volatile("" ::: "memory");
  __builtin_amdgcn_s_barrier();
  asm volatile("" ::: "memory");
}

// ---------------- avg pool k=4,s=1,p=1, write bf16 embedding ----------------
__global__ void k_avgpool2(const float* __restrict__ in, ushort* __restrict__ embB){
  int t = blockIdx.x*256 + threadIdx.x;
  if (t >= NB*HO2*HO2*C2) return;
  int c = t % C2; int r = t / C2;
  int j = r % HO2; r /= HO2;
  int i = r % HO2; int b = r / HO2;
  const float* plane = in + ((size_t)(b*C2 + c)*HIN2)*HIN2;
  float s = 0.f;
  #pragma unroll
  for (int di=0; di<4; ++di){
    int y = i - 1 + di;
    if ((unsigned)y >= HIN2) continue;
    #pragma unroll
    for (int dj=0; dj<4; ++dj){
      int x = j - 1 + dj;
      if ((unsigned)x < HIN2) s += plane[y*HIN2 + x];
    }
  }
  embB[((size_t)((b*HO2 + i)*HO2 + j))*CC + c] = f2bf(s * (1.f/16.f));
}

__global__ void k_avgpool3(const float* __restrict__ in, float* __restrict__ f3p){
  int t = blockIdx.x*256 + threadIdx.x;
  if (t >= NB*HO3*HO3*C3) return;
  int c = t % C3; int r = t / C3;
  int j = r % HO3; r /= HO3;
  int i = r % HO3; int b = r / HO3;
  const float* plane = in + ((size_t)(b*C3 + c)*HIN3)*HIN3;
  float s = 0.f;
  #pragma unroll
  for (int di=0; di<4; ++di){
    int y = i - 1 + di;
    if ((unsigned)y >= HIN3) continue;
    #pragma unroll
    for (int dj=0; dj<4; ++dj){
      int x = j - 1 + dj;
      if ((unsigned)x < HIN3) s += plane[y*HIN3 + x];
    }
  }
  f3p[((size_t)((b*HO3 + i)*HO3 + j))*C3 + c] = s * (1.f/16.f);
}

// ---------------- bilinear 13x13 -> 27x27 (half-pixel, clamp), write bf16 ----------------
__global__ void k_upsample3(const float* __restrict__ f3p, ushort* __restrict__ embB){
  int t = blockIdx.x*256 + threadIdx.x;
  if (t >= NB*HO2*HO2*C3) return;
  int c = t % C3; int r = t / C3;
  int ox = r % HO2; r /= HO2;
  int oy = r % HO2; int b = r / HO2;
  float fy = (oy + 0.5f) * (13.f/27.f) - 0.5f;
  float fx = (ox + 0.5f) * (13.f/27.f) - 0.5f;
  int y0 = (int)floorf(fy); float wy = fy - (float)y0;
  int x0 = (int)floorf(fx); float wx = fx - (float)x0;
  int y0c = min(max(y0,0), HO3-1), y1c = min(max(y0+1,0), HO3-1);
  int x0c = min(max(x0,0), HO3-1), x1c = min(max(x0+1,0), HO3-1);
  const float* base = f3p + (size_t)(b*HO3*HO3)*C3;
  float v00 = base[(size_t)(y0c*HO3 + x0c)*C3 + c];
  float v01 = base[(size_t)(y0c*HO3 + x1c)*C3 + c];
  float v10 = base[(size_t)(y1c*HO3 + x0c)*C3 + c];
  float v11 = base[(size_t)(y1c*HO3 + x1c)*C3 + c];
  float v = (1.f-wy)*((1.f-wx)*v00 + wx*v01) + wy*((1.f-wx)*v10 + wx*v11);
  embB[((size_t)((b*HO2 + oy)*HO2 + ox))*CC + C2 + c] = f2bf(v);
}

// ---------------- fused bank fp32->bf16 convert + row sum of squares ----------------
__global__ void k_bank_prep(const float* __restrict__ bank, ushort* __restrict__ bankB,
                            float* __restrict__ y2){
  int wave = threadIdx.x >> 6, lane = threadIdx.x & 63;
  int r = blockIdx.x*4 + wave;
  if (r >= NM) return;
  const float4* p = (const float4*)(bank + (size_t)r*CC);
  ushort4* q = (ushort4*)(bankB + (size_t)r*CC);
  float s = 0.f;
  #pragma unroll
  for (int it=0; it<6; ++it){
    float4 v = p[it*64 + lane];
    s += v.x*v.x + v.y*v.y + v.z*v.z + v.w*v.w;
    ushort4 o; o.x = f2bf(v.x); o.y = f2bf(v.y); o.z = f2bf(v.z); o.w = f2bf(v.w);
    q[it*64 + lane] = o;
  }
  s = warp_sum(s);
  if (lane==0) y2[r] = s;
}

__global__ void k_rowsumsq_bf(const ushort* __restrict__ src, float* __restrict__ dst, int rows){
  int wave = threadIdx.x >> 6;
  int lane = threadIdx.x & 63;
  int r = blockIdx.x*4 + wave;
  if (r >= rows) return;
  const uint4* p = (const uint4*)(src + (size_t)r*CC);
  float s = 0.f;
  #pragma unroll
  for (int it=0; it<3; ++it){
    uint4 v = p[it*64 + lane];
    u32 ws_[4] = {v.x, v.y, v.z, v.w};
    #pragma unroll
    for (int q=0;q<4;q++){
      float lo = __uint_as_float(ws_[q]<<16);
      float hi = __uint_as_float(ws_[q]&0xFFFF0000u);
      s += lo*lo + hi*hi;
    }
  }
  s = warp_sum(s);
  if (lane==0) dst[r] = s;
}

__global__ void k_init(u64* __restrict__ packed){
  int t = blockIdx.x*256 + threadIdx.x;
  if (t < NP) packed[t] = ~0ull;
}

// ---------------- fused bf16 MFMA distance GEMM + min/argmin ----------------
// 256x256 tile, BK=64, 8 waves (2Mx4N), double-buffered LDS, XOR-swizzled (T2).
// 4-phase-per-K-tile schedule (T3+T4+T5): each phase = {vmcnt(2)+barrier,
// 2 global_load_lds (quarter of next tile), ds_read a FUTURE cluster's frags,
// 16 MFMA (one C-quadrant)}. Per-wave load order A-lo,B-lo,B-hi,A-hi makes a
// uniform vmcnt(2) retire exactly the half-tile the phase is about to read.
__global__ __launch_bounds__(512, 2) void k_distmin_mfma(
    const ushort* __restrict__ A, const ushort* __restrict__ B,
    const float* __restrict__ x2, const float* __restrict__ y2,
    u64* __restrict__ packed)
{
  __shared__ ushort smem[4*BM*BK];   // [A0 | B0 | A1 | B1] = 128KB
  ushort* As0 = smem;
  ushort* Bs0 = smem + BM*BK;
  ushort* As1 = smem + 2*BM*BK;
  ushort* Bs1 = smem + 3*BM*BK;

  const int tid = threadIdx.x;
  const int w   = tid >> 6;          // wave 0..7
  const int l   = tid & 63;
  const int wr  = w >> 2;            // 0..1  (M: wr*128)
  const int wc  = w & 3;             // 0..3  (N: wc*64)
  const int ccol = l & 15;
  const int cgrp = l >> 4;

  // bijective XCD swizzle (m204): nwg=2875
  int orig = blockIdx.x;
  const int q8 = NWG/8, r8 = NWG%8;
  int xcd = orig & 7, sidx = orig >> 3;
  int wg = (xcd < r8 ? xcd*(q8+1) : r8*(q8+1) + (xcd-r8)*q8) + sidx;
  const int mb = wg % MB_CNT;        // M fastest: consecutive wgs share B-panel
  const int nb = wg / MB_CNT;
  const int m0 = mb * BM;
  const int n0 = nb * BN;

  // Staging chunks (8 rows x 64 cols = 1KB each, 32 per matrix).
  // Half-tile groups match per-wave consumption:
  //  A-first : tile rows 0-63,128-191  (chunks 0-7,16-23)   -> rAlo (mi 0-3)
  //  A-second: rows 64-127,192-255     (chunks 8-15,24-31)  -> rAhi (mi 4-7)
  //  B-first : rows {0-31 mod 64}      (chunks 0-3,8-11,16-19,24-27) -> rBlo
  //  B-second: rows {32-63 mod 64}     (+4)                 -> rBhi
  const int rowin = l >> 3;                    // row within chunk
  const int scol  = (((l&7) ^ rowin) * 8);     // swizzled source segment (T2)
  int chA1[2], chA2[2], chB1[2], chB2[2];
  u32 aO1[2], aO2[2], bO1[2], bO2[2];          // global element offsets (k=0)
  u32 lA1[2], lA2[2], lB1[2], lB2[2];          // LDS byte offsets within region
  #pragma unroll
  for (int c=0;c<2;c++){
    chA1[c] = (w<4) ? (2*w+c) : (8+2*w+c);
    chA2[c] = chA1[c] + 8;
    chB1[c] = (w>>1)*8 + (w&1)*2 + c;
    chB2[c] = chB1[c] + 4;
    aO1[c] = (u32)min(m0 + chA1[c]*8 + rowin, NP-1)*CC + scol;
    aO2[c] = (u32)min(m0 + chA2[c]*8 + rowin, NP-1)*CC + scol;
    bO1[c] = (u32)(n0 + chB1[c]*8 + rowin)*CC + scol;
    bO2[c] = (u32)(n0 + chB2[c]*8 + rowin)*CC + scol;
    lA1[c] = (u32)chA1[c]*1024 + l*16;
    lA2[c] = (u32)chA2[c]*1024 + l*16;
    lB1[c] = (u32)chB1[c]*1024 + l*16;
    lB2[c] = (u32)chB2[c]*1024 + l*16;
  }

  // fragment read bases (ushort units); seg XOR: o(ks) = o0 ^ (ks<<5)
  const u32 o0 = (u32)((cgrp ^ (ccol & 7)) * 8);
  u32 aRow[8], bRow[4];
  #pragma unroll
  for (int mi=0;mi<8;mi++) aRow[mi] = (u32)(wr*128 + mi*16 + ccol)*BK;
  #pragma unroll
  for (int ni=0;ni<4;ni++) bRow[ni] = (u32)(wc*64 + ni*16 + ccol)*BK;

  f32x4 acc[8][4];
  #pragma unroll
  for (int mi=0;mi<8;mi++)
    #pragma unroll
    for (int ni=0;ni<4;ni++)
      acc[mi][ni] = (f32x4){0.f,0.f,0.f,0.f};

  bf16x8 rAlo[4][2], rAhi[4][2], rBlo[2][2], rBhi[2][2];

  // -------- prologue: tile 0 --------
  #pragma unroll
  for (int c=0;c<2;c++) GLDS(A + aO1[c], (char*)As0 + lA1[c]);
  #pragma unroll
  for (int c=0;c<2;c++) GLDS(B + bO1[c], (char*)Bs0 + lB1[c]);
  WAITVM0(); bar_raw();
  #pragma unroll
  for (int mi=0;mi<4;mi++)
    #pragma unroll
    for (int ks=0;ks<2;ks++)
      rAlo[mi][ks] = *(const bf16x8*)&As0[aRow[mi] + (o0 ^ (u32)(ks<<5))];
  #pragma unroll
  for (int ni=0;ni<2;ni++)
    #pragma unroll
    for (int ks=0;ks<2;ks++)
      rBlo[ni][ks] = *(const bf16x8*)&Bs0[bRow[ni] + (o0 ^ (u32)(ks<<5))];
  #pragma unroll
  for (int c=0;c<2;c++) GLDS(B + bO2[c], (char*)Bs0 + lB2[c]);
  #pragma unroll
  for (int c=0;c<2;c++) GLDS(A + aO2[c], (char*)As0 + lA2[c]);
  // outstanding: [B-hi(0) x2, A-hi(0) x2]

  const ushort* cA = As0; const ushort* cB = Bs0;
  ushort* nA = As1; ushort* nB = Bs1;

  #pragma unroll 1
  for (int kt=0; kt<KT; ++kt){
    const u32 kk = (u32)(kt+1)*BK;   // next-tile k offset (harmless ws-garbage at kt=KT-1)

    // ---- P0: Q00 (rAlo x rBlo); read rBhi(cur); stage A-lo(next)
    WAITVM2(); bar_raw(); __builtin_amdgcn_sched_barrier(0);
    GLDS(A + aO1[0] + kk, (char*)nA + lA1[0]);
    GLDS(A + aO1[1] + kk, (char*)nA + lA1[1]);
    #pragma unroll
    for (int ni=0;ni<2;ni++)
      #pragma unroll
      for (int ks=0;ks<2;ks++)
        rBhi[ni][ks] = *(const bf16x8*)&cB[bRow[ni+2] + (o0 ^ (u32)(ks<<5))];
    __builtin_amdgcn_s_setprio(1);
    #pragma unroll
    for (int mi=0;mi<4;mi++)
      #pragma unroll
      for (int ni=0;ni<2;ni++)
        #pragma unroll
        for (int ks=0;ks<2;ks++)
          acc[mi][ni] = __builtin_amdgcn_mfma_f32_16x16x32_bf16(rAlo[mi][ks], rBlo[ni][ks], acc[mi][ni], 0, 0, 0);
    __builtin_amdgcn_s_setprio(0);

    // ---- P1: Q01 (rAlo x rBhi); read rAhi(cur); stage B-lo(next)
    WAITVM2(); bar_raw(); __builtin_amdgcn_sched_barrier(0);
    GLDS(B + bO1[0] + kk, (char*)nB + lB1[0]);
    GLDS(B + bO1[1] + kk, (char*)nB + lB1[1]);
    #pragma unroll
    for (int mi=0;mi<4;mi++)
      #pragma unroll
      for (int ks=0;ks<2;ks++)
        rAhi[mi][ks] = *(const bf16x8*)&cA[aRow[mi+4] + (o0 ^ (u32)(ks<<5))];
    __builtin_amdgcn_s_setprio(1);
    #pragma unroll
    for (int mi=0;mi<4;mi++)
      #pragma unroll
      for (int ni=0;ni<2;ni++)
        #pragma unroll
        for (int ks=0;ks<2;ks++)
          acc[mi][ni+2] = __builtin_amdgcn_mfma_f32_16x16x32_bf16(rAlo[mi][ks], rBhi[ni][ks], acc[mi][ni+2], 0, 0, 0);
    __builtin_amdgcn_s_setprio(0);

    // ---- P2: Q10 (rAhi x rBlo); read rAlo(NEXT); stage B-hi(next)
    WAITVM2(); bar_raw(); __builtin_amdgcn_sched_barrier(0);
    GLDS(B + bO2[0] + kk, (char*)nB + lB2[0]);
    GLDS(B + bO2[1] + kk, (char*)nB + lB2[1]);
    #pragma unroll
    for (int mi=0;mi<4;mi++)
      #pragma unroll
      for (int ks=0;ks<2;ks++)
        rAlo[mi][ks] = *(const bf16x8*)&((const ushort*)nA)[aRow[mi] + (o0 ^ (u32)(ks<<5))];
    __builtin_amdgcn_s_setprio(1);
    #pragma unroll
    for (int mi=0;mi<4;mi++)
      #pragma unroll
      for (int ni=0;ni<2;ni++)
        #pragma unroll
        for (int ks=0;ks<2;ks++)
          acc[mi+4][ni] = __builtin_amdgcn_mfma_f32_16x16x32_bf16(rAhi[mi][ks], rBlo[ni][ks], acc[mi+4][ni], 0, 0, 0);
    __builtin_amdgcn_s_setprio(0);

    // ---- P3: Q11 (rAhi x rBhi); read rBlo(NEXT); stage A-hi(next)
    WAITVM2(); bar_raw(); __builtin_amdgcn_sched_barrier(0);
    GLDS(A + aO2[0] + kk, (char*)nA + lA2[0]);
    GLDS(A + aO2[1] + kk, (char*)nA + lA2[1]);
    #pragma unroll
    for (int ni=0;ni<2;ni++)
      #pragma unroll
      for (int ks=0;ks<2;ks++)
        rBlo[ni][ks] = *(const bf16x8*)&((const ushort*)nB)[bRow[ni] + (o0 ^ (u32)(ks<<5))];
    __builtin_amdgcn_s_setprio(1);
    #pragma unroll
    for (int mi=0;mi<4;mi++)
      #pragma unroll
      for (int ni=0;ni<2;ni++)
        #pragma unroll
        for (int ks=0;ks<2;ks++)
          acc[mi+4][ni+2] = __builtin_amdgcn_mfma_f32_16x16x32_bf16(rAhi[mi][ks], rBhi[ni][ks], acc[mi+4][ni+2], 0, 0, 0);
    __builtin_amdgcn_s_setprio(0);

    // swap buffers
    ushort* t1 = (ushort*)cA; cA = nA; nA = t1;
    ushort* t2 = (ushort*)cB; cB = nB; nB = t2;
  }
  WAITVM0();   // drain tail garbage loads before LDS goes away

  // epilogue: d2 = x2 + y2 - 2*dot ; min over this block's 256 columns, then atomicMin
  float xv[8][4];
  #pragma unroll
  for (int mi=0;mi<8;mi++)
    #pragma unroll
    for (int r=0;r<4;r++)
      xv[mi][r] = x2[min(m0 + wr*128 + mi*16 + cgrp*4 + r, NP-1)];

  u64 best[8][4];
  #pragma unroll
  for (int mi=0;mi<8;mi++)
    #pragma unroll
    for (int r=0;r<4;r++) best[mi][r] = ~0ull;

  #pragma unroll
  for (int ni=0;ni<4;ni++){
    const int n = n0 + wc*64 + ni*16 + ccol;
    const float yy = y2[n];
    #pragma unroll
    for (int mi=0;mi<8;mi++)
      #pragma unroll
      for (int r=0;r<4;r++){
        float d2 = fmaxf(xv[mi][r] + yy - 2.f*acc[mi][ni][r], 0.f);
        u64 pk = (((u64)__float_as_uint(d2))<<32) | (u32)n;
        if (pk < best[mi][r]) best[mi][r] = pk;
      }
  }

  #pragma unroll
  for (int mi=0;mi<8;mi++)
    #pragma unroll
    for (int r=0;r<4;r++){
      u64 pk = best[mi][r];
      #pragma unroll
      for (int md=1; md<16; md<<=1){
        u64 o = __shfl_xor(pk, md);
        if (o < pk) pk = o;
      }
      const int row = m0 + wr*128 + mi*16 + cgrp*4 + r;
      if (ccol==0 && row < NP) atomicMin(&packed[row], pk);
    }
}

__global__ void k_unpack(const u64* __restrict__ packed, float* __restrict__ patch_d, int* __restrict__ loc){
  int t = blockIdx.x*256 + threadIdx.x;
  if (t < NP){
    u64 v = packed[t];
    patch_d[t] = sqrtf(__uint_as_float((u32)(v>>32)));
    loc[t] = (int)(v & 0xffffffffu);
  }
}

// ---------------- per-batch argmax of patch scores ----------------
__global__ void k_argmax(const float* __restrict__ patch_d, const int* __restrict__ loc,
                         int* __restrict__ sel_mp, float* __restrict__ sel_score, int* __restrict__ sel_nn){
  int b = blockIdx.x;
  int tid = threadIdx.x;
  __shared__ u64 red[4];
  u64 best = 0;
  for (int p = tid; p < HO2*HO2; p += 256){
    float v = patch_d[b*HO2*HO2 + p];
    u64 pk = (((u64)__float_as_uint(v))<<32) | (u32)(HO2*HO2 - p);  // tie -> smaller p wins on max
    if (pk > best) best = pk;
  }
  int lane = tid & 63, w = tid >> 6;
  #pragma unroll
  for (int d=32; d; d>>=1){ u64 o = __shfl_down(best, d); if (o > best) best = o; }
  if (lane==0) red[w] = best;
  __syncthreads();
  if (tid==0){
    u64 bb = red[0];
    for (int q=1;q<4;q++) if (red[q] > bb) bb = red[q];
    int p = HO2*HO2 - (int)(bb & 0xffffffffu);
    sel_mp[b] = p;
    sel_score[b] = __uint_as_float((u32)(bb>>32));
    sel_nn[b] = loc[b*HO2*HO2 + p];
  }
}

// ---------------- d2(nn_sample[b], bank[m]) for all b,m (bf16 bank) ----------------
__device__ __forceinline__ void bf8dec(uint4 v, float* f){
  u32 a[4] = {v.x, v.y, v.z, v.w};
  #pragma unroll
  for (int q=0;q<4;q++){
    f[2*q]   = __uint_as_float(a[q]<<16);
    f[2*q+1] = __uint_as_float(a[q]&0xFFFF0000u);
  }
}

__global__ __launch_bounds__(256) void k_dbank(const ushort* __restrict__ bankB, const float* __restrict__ y2,
    const int* __restrict__ sel_nn, float* __restrict__ d_bank){
  int wave = threadIdx.x >> 6, lane = threadIdx.x & 63;
  int m = blockIdx.x*4 + wave;
  if (m >= NM) return;
  int nn[NB];
  #pragma unroll
  for (int b=0;b<NB;b++) nn[b] = sel_nn[b];
  const uint4* pm = (const uint4*)(bankB + (size_t)m*CC);
  float acc[NB];
  #pragma unroll
  for (int b=0;b<NB;b++) acc[b] = 0.f;
  #pragma unroll
  for (int it=0; it<3; ++it){
    uint4 v = pm[it*64 + lane];
    float vf[8]; bf8dec(v, vf);
    #pragma unroll
    for (int b=0;b<NB;b++){
      uint4 u = ((const uint4*)(bankB + (size_t)nn[b]*CC))[it*64 + lane];
      float uf[8]; bf8dec(u, uf);
      #pragma unroll
      for (int q=0;q<8;q++) acc[b] += vf[q]*uf[q];
    }
  }
  #pragma unroll
  for (int b=0;b<NB;b++){
    float s = warp_sum(acc[b]);
    if (lane==0) d_bank[(size_t)b*NM + m] = fmaxf(y2[nn[b]] + y2[m] - 2.f*s, 0.f);
  }
}

// ---------------- single-pass top-9 + anomaly score ----------------
__global__ __launch_bounds__(256) void k_score(const float* __restrict__ d_bank, const float* __restrict__ bank,
    const ushort* __restrict__ embB, const float* __restrict__ x2, const float* __restrict__ y2,
    const int* __restrict__ sel_mp, const float* __restrict__ sel_score, float* __restrict__ out_score){
  int b = blockIdx.x, tid = threadIdx.x;
  __shared__ u64 cand[256*NKNN];
  __shared__ int sel[NKNN];
  __shared__ u64 red[4];
  __shared__ u64 gbest_s;
  __shared__ float fred[4];
  __shared__ float sumexp_s;

  #pragma unroll
  for (int q=0;q<NKNN;q++) cand[tid*NKNN+q] = ~0ull;
  for (int m = tid; m < NM; m += 256){
    float v = d_bank[(size_t)b*NM + m];
    u64 pk = (((u64)__float_as_uint(v))<<32) | (u32)m;
    if (pk < cand[tid*NKNN + NKNN-1]){
      cand[tid*NKNN + NKNN-1] = pk;
      for (int q=NKNN-1; q>0 && cand[tid*NKNN+q] < cand[tid*NKNN+q-1]; --q){
        u64 t = cand[tid*NKNN+q]; cand[tid*NKNN+q] = cand[tid*NKNN+q-1]; cand[tid*NKNN+q-1] = t;
      }
    }
  }
  __syncthreads();
  int lane = tid & 63, w = tid >> 6;
  for (int k=0;k<NKNN;++k){
    u64 mybest = ~0ull;
    #pragma unroll
    for (int q=0;q<NKNN;q++){ u64 v = cand[tid*NKNN+q]; if (v < mybest) mybest = v; }
    u64 rb = mybest;
    #pragma unroll
    for (int d=32; d; d>>=1){ u64 o = __shfl_down(rb, d); if (o < rb) rb = o; }
    if (lane==0) red[w] = rb;
    __syncthreads();
    if (tid==0){
      u64 bb = red[0];
      for (int q=1;q<4;q++) if (red[q] < bb) bb = red[q];
      gbest_s = bb;
      sel[k] = (int)(bb & 0xffffffffu);
    }
    __syncthreads();
    u64 gb = gbest_s;
    #pragma unroll
    for (int q=0;q<NKNN;q++) if (cand[tid*NKNN+q] == gb) cand[tid*NKNN+q] = ~0ull;
    __syncthreads();
  }

  int mp = sel_mp[b];
  const ushort* fv = embB + (size_t)(b*HO2*HO2 + mp)*CC;
  float fx2 = x2[b*HO2*HO2 + mp];
  if (tid==0) sumexp_s = 0.f;
  __syncthreads();
  for (int k=0;k<NKNN;++k){
    const float* sv = bank + (size_t)sel[k]*CC;
    float part = 0.f;
    for (int i = tid; i < CC; i += 256) part += bf2f(fv[i])*sv[i];
    part = warp_sum(part);
    if (lane==0) fred[w] = part;
    __syncthreads();
    if (tid==0){
      float dot = fred[0]+fred[1]+fred[2]+fred[3];
      float d2 = fmaxf(fx2 + y2[sel[k]] - 2.f*dot, 0.f);
      sumexp_s += expf(sqrtf(d2));
    }
    __syncthreads();
  }
  if (tid==0){
    float s = sel_score[b];
    out_score[b] = (1.f - expf(s)/sumexp_s) * s;
  }
}

// ---------------- anomaly map: bilinear 27 -> 224, then separable gaussian ----------------
__global__ void k_amap_bilinear(const float* __restrict__ patch_d, float* __restrict__ amap){
  int t = blockIdx.x*256 + threadIdx.x;
  if (t >= AMAP_N) return;
  int x = t % OH; int r = t / OH;
  int y = r % OH; int b = r / OH;
  float fy = (y + 0.5f) * (27.f/224.f) - 0.5f;
  float fx = (x + 0.5f) * (27.f/224.f) - 0.5f;
  int y0 = (int)floorf(fy); float wy = fy - (float)y0;
  int x0 = (int)floorf(fx); float wx = fx - (float)x0;
  int y0c = min(max(y0,0),HO2-1), y1c = min(max(y0+1,0),HO2-1);
  int x0c = min(max(x0,0),HO2-1), x1c = min(max(x0+1,0),HO2-1);
  const float* p = patch_d + b*HO2*HO2;
  float v = (1.f-wy)*((1.f-wx)*p[y0c*HO2+x0c] + wx*p[y0c*HO2+x1c])
          + wy*((1.f-wx)*p[y1c*HO2+x0c] + wx*p[y1c*HO2+x1c]);
  amap[t] = v;
}

__global__ void k_blur_h(const float* __restrict__ in, float* __restrict__ out, GW gw){
  int t = blockIdx.x*256 + threadIdx.x;
  if (t >= AMAP_N) return;
  int x = t % OH; int rest = t / OH;
  const float* row = in + (size_t)rest*OH;
  float s = 0.f;
  #pragma unroll
  for (int k=0;k<33;++k){
    int xx = x + k - 16;
    xx = (xx < 0) ? -xx : xx;
    xx = (xx > OH-1) ? (2*(OH-1) - xx) : xx;
    s += gw.w[k]*row[xx];
  }
  out[t] = s;
}

__global__ void k_blur_v(const float* __restrict__ in, float* __restrict__ out, GW gw){
  int t = blockIdx.x*256 + threadIdx.x;
  if (t >= AMAP_N) return;
  int x = t % OH; int r = t / OH;
  int y = r % OH; int b = r / OH;
  const float* img = in + (size_t)b*OH*OH;
  float s = 0.f;
  #pragma unroll
  for (int k=0;k<33;++k){
    int yy = y + k - 16;
    yy = (yy < 0) ? -yy : yy;
    yy = (yy > OH-1) ? (2*(OH-1) - yy) : yy;
    s += gw.w[k]*img[(size_t)yy*OH + x];
  }
  out[t] = s;
}

extern "C" void kernel_launch(void* const* d_in, const int* in_sizes, int n_in,
                              void* d_out, int out_size, void* d_ws, size_t ws_size,
                              hipStream_t stream){
  const float* f2   = (const float*)d_in[0];
  const float* f3   = (const float*)d_in[1];
  const float* bank = (const float*)d_in[2];
  float* out = (float*)d_out;

  char* ws = (char*)d_ws;
  size_t off = 0;
  auto alloc = [&](size_t bytes)->char*{ char* p = ws + off; off += (bytes + 255) & ~(size_t)255; return p; };
  ushort* embB    = (ushort*)alloc((size_t)NP*CC*2);
  ushort* bankB   = (ushort*)alloc((size_t)NM*CC*2);
  float* f3p      = (float*)alloc((size_t)NB*HO3*HO3*C3*4);
  float* y2       = (float*)alloc((size_t)NM*4);
  float* x2       = (float*)alloc((size_t)NP*4);
  u64*   packed   = (u64*)  alloc((size_t)NP*8);
  float* patch_d  = (float*)alloc((size_t)NP*4);
  int*   loc      = (int*)  alloc((size_t)NP*4);
  float* d_bank   = (float*)alloc((size_t)NB*NM*4);
  int*   sel_mp   = (int*)  alloc(NB*4);
  float* sel_scr  = (float*)alloc(NB*4);
  int*   sel_nn   = (int*)  alloc(NB*4);
  float* amap1    = (float*)alloc((size_t)AMAP_N*4);
  float* amap2    = (float*)alloc((size_t)AMAP_N*4);

  GW gw;
  { float s=0.f; for(int i=0;i<33;i++){ float xx=(float)i-16.f; gw.w[i]=expf(-0.5f*(xx/4.f)*(xx/4.f)); s+=gw.w[i]; }
    for(int i=0;i<33;i++) gw.w[i]/=s; }

  k_avgpool2<<<(NB*HO2*HO2*C2+255)/256,256,0,stream>>>(f2, embB);
  k_avgpool3<<<(NB*HO3*HO3*C3+255)/256,256,0,stream>>>(f3, f3p);
  k_upsample3<<<(NB*HO2*HO2*C3+255)/256,256,0,stream>>>(f3p, embB);
  k_bank_prep<<<(NM+3)/4,256,0,stream>>>(bank, bankB, y2);
  k_rowsumsq_bf<<<(NP+3)/4,256,0,stream>>>(embB, x2, NP);
  k_init<<<(NP+255)/256,256,0,stream>>>(packed);
  k_distmin_mfma<<<NWG,512,0,stream>>>(embB, bankB, x2, y2, packed);
  k_unpack<<<(NP+255)/256,256,0,stream>>>(packed, patch_d, loc);
  k_argmax<<<NB,256,0,stream>>>(patch_d, loc, sel_mp, sel_scr, sel_nn);
  k_dbank<<<(NM+3)/4,256,0,stream>>>(bankB, y2, sel_nn, d_bank);
  k_score<<<NB,256,0,stream>>>(d_bank, bank, embB, x2, y2, sel_mp, sel_scr, out + AMAP_N);
  k_amap_bilinear<<<(AMAP_N+255)/256,256,0,stream>>>(patch_d, amap1);
  k_blur_h<<<(AMAP_N+255)/256,256,0,stream>>>(amap1, amap2, gw);
  k_blur_v<<<(AMAP_N+255)/256,256,0,stream>>>(amap2, out, gw);
}

// Round 6
// 949.617 us; speedup vs baseline: 9.8054x; 1.0967x over previous
//
#include <hip/hip_runtime.h>
#include <math.h>

#define NB 8
#define C2 512
#define C3 1024
#define HIN2 28
#define HIN3 14
#define HO2 27
#define HO3 13
#define CC 1536
#define NP (NB*HO2*HO2)   /* 5832 */
#define NM 32000
#define NKNN 9
#define OH 224
#define AMAP_N (NB*OH*OH) /* 401408 */

/* 256x256 tile GEMM geometry */
#define BM 256
#define BN 256
#define BK 64
#define KT (CC/BK)        /* 24 */
#define MB_CNT ((NP+BM-1)/BM)   /* 23 */
#define NB_CNT (NM/BN)          /* 125 */
#define NWG (MB_CNT*NB_CNT)     /* 2875 */

typedef unsigned long long u64;
typedef unsigned int u32;
typedef __attribute__((ext_vector_type(8))) short bf16x8;
typedef __attribute__((ext_vector_type(4))) float f32x4;

struct GW { float w[33]; };

__device__ __forceinline__ float warp_sum(float v){
  #pragma unroll
  for (int off=32; off; off>>=1) v += __shfl_down(v, off);
  return v;
}

__device__ __forceinline__ ushort f2bf(float f){
  u32 u = __float_as_uint(f);
  u32 r = (u + 0x7FFFu + ((u>>16)&1u)) >> 16;
  return (ushort)r;
}
__device__ __forceinline__ float bf2f(ushort b){
  return __uint_as_float(((u32)b)<<16);
}

#define GLDS(g, l) __builtin_amdgcn_global_load_lds((const __attribute__((address_space(1))) void*)(g), (__attribute__((address_space(3))) void*)(l), 16, 0, 0)
#define WAITVM4() asm volatile("s_waitcnt vmcnt(4)" ::: "memory")
#define WAITVM0() asm volatile("s_waitcnt vmcnt(0)" ::: "memory")
#define WAITLGKM0() asm volatile("s_waitcnt lgkmcnt(0)" ::: "memory")
#define SB0() __builtin_amdgcn_sched_barrier(0)
__device__ __forceinline__ void bar_raw(){
  asm volatile("" ::: "memory");
  __builtin_amdgcn_s_barrier();
  asm volatile("" ::: "memory");
}

// ---------------- avg pool k=4,s=1,p=1 (LDS-tiled transpose), write bf16 emb ----------------
// block = (b, 16-channel group). Coalesced NCHW plane loads -> LDS -> NHWC bf16 writes.
__global__ __launch_bounds__(256) void k_avgpool2(const float* __restrict__ in, ushort* __restrict__ embB){
  __shared__ float pl[16*789];   // pad 789: c*789%32 distinct for c=0..15 -> conflict-free
  int b = blockIdx.x >> 5, cg = blockIdx.x & 31;
  const float4* src = (const float4*)(in + ((size_t)b*C2 + cg*16)*(HIN2*HIN2));
  for (int idx = threadIdx.x; idx < 16*196; idx += 256){
    int c = idx/196, p4 = idx - c*196;
    float4 v = src[idx];
    float* d = &pl[c*789 + p4*4];
    d[0]=v.x; d[1]=v.y; d[2]=v.z; d[3]=v.w;
  }
  __syncthreads();
  int c = threadIdx.x & 15, g = threadIdx.x >> 4;
  for (int pos = g; pos < HO2*HO2; pos += 16){
    int i = pos/HO2, j = pos - i*HO2;
    const float* p = &pl[c*789];
    float s = 0.f;
    #pragma unroll
    for (int di=0; di<4; ++di){
      int y = i - 1 + di;
      if ((unsigned)y >= HIN2) continue;
      #pragma unroll
      for (int dj=0; dj<4; ++dj){
        int x = j - 1 + dj;
        if ((unsigned)x < HIN2) s += p[y*HIN2 + x];
      }
    }
    embB[((size_t)((b*HO2 + i)*HO2 + j))*CC + cg*16 + c] = f2bf(s * (1.f/16.f));
  }
}

// block = (b, 64-channel group)
__global__ __launch_bounds__(256) void k_avgpool3(const float* __restrict__ in, float* __restrict__ f3p){
  __shared__ float pl[64*197];   // pad 197: c*197%32 = c*5%32 -> 2-way max (free)
  int b = blockIdx.x >> 4, cg = blockIdx.x & 15;
  const float4* src = (const float4*)(in + ((size_t)b*C3 + cg*64)*(HIN3*HIN3));
  for (int idx = threadIdx.x; idx < 64*49; idx += 256){
    int c = idx/49, p4 = idx - c*49;
    float4 v = src[idx];
    float* d = &pl[c*197 + p4*4];
    d[0]=v.x; d[1]=v.y; d[2]=v.z; d[3]=v.w;
  }
  __syncthreads();
  int c = threadIdx.x & 63, g = threadIdx.x >> 6;
  for (int pos = g; pos < HO3*HO3; pos += 4){
    int i = pos/HO3, j = pos - i*HO3;
    const float* p = &pl[c*197];
    float s = 0.f;
    #pragma unroll
    for (int di=0; di<4; ++di){
      int y = i - 1 + di;
      if ((unsigned)y >= HIN3) continue;
      #pragma unroll
      for (int dj=0; dj<4; ++dj){
        int x = j - 1 + dj;
        if ((unsigned)x < HIN3) s += p[y*HIN3 + x];
      }
    }
    f3p[((size_t)((b*HO3 + i)*HO3 + j))*C3 + cg*64 + c] = s * (1.f/16.f);
  }
}

// ---------------- bilinear 13x13 -> 27x27 (half-pixel, clamp), write bf16 ----------------
__global__ void k_upsample3(const float* __restrict__ f3p, ushort* __restrict__ embB){
  int t = blockIdx.x*256 + threadIdx.x;
  if (t >= NB*HO2*HO2*C3) return;
  int c = t % C3; int r = t / C3;
  int ox = r % HO2; r /= HO2;
  int oy = r % HO2; int b = r / HO2;
  float fy = (oy + 0.5f) * (13.f/27.f) - 0.5f;
  float fx = (ox + 0.5f) * (13.f/27.f) - 0.5f;
  int y0 = (int)floorf(fy); float wy = fy - (float)y0;
  int x0 = (int)floorf(fx); float wx = fx - (float)x0;
  int y0c = min(max(y0,0), HO3-1), y1c = min(max(y0+1,0), HO3-1);
  int x0c = min(max(x0,0), HO3-1), x1c = min(max(x0+1,0), HO3-1);
  const float* base = f3p + (size_t)(b*HO3*HO3)*C3;
  float v00 = base[(size_t)(y0c*HO3 + x0c)*C3 + c];
  float v01 = base[(size_t)(y0c*HO3 + x1c)*C3 + c];
  float v10 = base[(size_t)(y1c*HO3 + x0c)*C3 + c];
  float v11 = base[(size_t)(y1c*HO3 + x1c)*C3 + c];
  float v = (1.f-wy)*((1.f-wx)*v00 + wx*v01) + wy*((1.f-wx)*v10 + wx*v11);
  embB[((size_t)((b*HO2 + oy)*HO2 + ox))*CC + C2 + c] = f2bf(v);
}

// ---------------- fused bank fp32->bf16 convert + row sum of squares ----------------
__global__ void k_bank_prep(const float* __restrict__ bank, ushort* __restrict__ bankB,
                            float* __restrict__ y2){
  int wave = threadIdx.x >> 6, lane = threadIdx.x & 63;
  int r = blockIdx.x*4 + wave;
  if (r >= NM) return;
  const float4* p = (const float4*)(bank + (size_t)r*CC);
  ushort4* q = (ushort4*)(bankB + (size_t)r*CC);
  float s = 0.f;
  #pragma unroll
  for (int it=0; it<6; ++it){
    float4 v = p[it*64 + lane];
    s += v.x*v.x + v.y*v.y + v.z*v.z + v.w*v.w;
    ushort4 o; o.x = f2bf(v.x); o.y = f2bf(v.y); o.z = f2bf(v.z); o.w = f2bf(v.w);
    q[it*64 + lane] = o;
  }
  s = warp_sum(s);
  if (lane==0) y2[r] = s;
}

// also initializes packed[] (rows == NP)
__global__ void k_rowsumsq_bf(const ushort* __restrict__ src, float* __restrict__ dst, int rows,
                              u64* __restrict__ packed){
  int wave = threadIdx.x >> 6;
  int lane = threadIdx.x & 63;
  int r = blockIdx.x*4 + wave;
  if (r >= rows) return;
  const uint4* p = (const uint4*)(src + (size_t)r*CC);
  float s = 0.f;
  #pragma unroll
  for (int it=0; it<3; ++it){
    uint4 v = p[it*64 + lane];
    u32 ws_[4] = {v.x, v.y, v.z, v.w};
    #pragma unroll
    for (int q=0;q<4;q++){
      float lo = __uint_as_float(ws_[q]<<16);
      float hi = __uint_as_float(ws_[q]&0xFFFF0000u);
      s += lo*lo + hi*hi;
    }
  }
  s = warp_sum(s);
  if (lane==0){ dst[r] = s; packed[r] = ~0ull; }
}

// ---------------- fused bf16 MFMA distance GEMM + min/argmin ----------------
// m201-style phase schedule: same-phase ds_reads before barrier, lgkmcnt(0) after,
// 2 barriers/phase (lockstep), counted vmcnt(4) BEFORE the phase-ending barrier
// (barrier makes per-wave vmcnt a cross-wave guarantee). XOR-swizzle (T2), setprio (T5).
__global__ __launch_bounds__(512, 2) void k_distmin_mfma(
    const ushort* __restrict__ A, const ushort* __restrict__ B,
    const float* __restrict__ x2, const float* __restrict__ y2,
    u64* __restrict__ packed)
{
  __shared__ ushort smem[4*BM*BK];   // [A0 | B0 | A1 | B1] = 128KB
  ushort* As0 = smem;
  ushort* Bs0 = smem + BM*BK;
  ushort* As1 = smem + 2*BM*BK;
  ushort* Bs1 = smem + 3*BM*BK;

  const int tid = threadIdx.x;
  const int w   = tid >> 6;          // wave 0..7
  const int l   = tid & 63;
  const int wr  = w >> 2;            // 0..1  (M: wr*128)
  const int wc  = w & 3;             // 0..3  (N: wc*64)
  const int ccol = l & 15;
  const int cgrp = l >> 4;

  // bijective XCD swizzle (m204): nwg=2875
  int orig = blockIdx.x;
  const int q8 = NWG/8, r8 = NWG%8;
  int xcd = orig & 7, sidx = orig >> 3;
  int wg = (xcd < r8 ? xcd*(q8+1) : r8*(q8+1) + (xcd-r8)*q8) + sidx;
  const int mb = wg % MB_CNT;
  const int nb = wg / MB_CNT;
  const int m0 = mb * BM;
  const int n0 = nb * BN;

  // Staging chunks (8 rows x 64 cols = 1KB each, 32 per matrix); half-tile groups:
  //  A-lo: chunks 0-7,16-23 (rows 0-63,128-191) -> rAlo (mi 0-3)
  //  A-hi: +8                                    -> rAhi (mi 4-7)
  //  B-lo: chunks {0-3 mod 8}                    -> rBlo (ni 0-1)
  //  B-hi: +4                                    -> rBhi (ni 2-3)
  const int rowin = l >> 3;
  const int scol  = (((l&7) ^ rowin) * 8);     // swizzled source segment (T2)
  int chA1[2], chA2[2], chB1[2], chB2[2];
  u32 aO1[2], aO2[2], bO1[2], bO2[2];
  u32 lA1[2], lA2[2], lB1[2], lB2[2];
  #pragma unroll
  for (int c=0;c<2;c++){
    chA1[c] = (w<4) ? (2*w+c) : (8+2*w+c);
    chA2[c] = chA1[c] + 8;
    chB1[c] = (w>>1)*8 + (w&1)*2 + c;
    chB2[c] = chB1[c] + 4;
    aO1[c] = (u32)min(m0 + chA1[c]*8 + rowin, NP-1)*CC + scol;
    aO2[c] = (u32)min(m0 + chA2[c]*8 + rowin, NP-1)*CC + scol;
    bO1[c] = (u32)(n0 + chB1[c]*8 + rowin)*CC + scol;
    bO2[c] = (u32)(n0 + chB2[c]*8 + rowin)*CC + scol;
    lA1[c] = (u32)chA1[c]*1024 + l*16;
    lA2[c] = (u32)chA2[c]*1024 + l*16;
    lB1[c] = (u32)chB1[c]*1024 + l*16;
    lB2[c] = (u32)chB2[c]*1024 + l*16;
  }

  const u32 o0 = (u32)((cgrp ^ (ccol & 7)) * 8);
  u32 aRow[8], bRow[4];
  #pragma unroll
  for (int mi=0;mi<8;mi++) aRow[mi] = (u32)(wr*128 + mi*16 + ccol)*BK;
  #pragma unroll
  for (int ni=0;ni<4;ni++) bRow[ni] = (u32)(wc*64 + ni*16 + ccol)*BK;

  f32x4 acc[8][4];
  #pragma unroll
  for (int mi=0;mi<8;mi++)
    #pragma unroll
    for (int ni=0;ni<4;ni++)
      acc[mi][ni] = (f32x4){0.f,0.f,0.f,0.f};

  bf16x8 rAlo[4][2], rAhi[4][2], rBlo[2][2], rBhi[2][2];

  // -------- prologue: stage tile 0 in canonical order A-lo, B-lo, B-hi, A-hi --------
  GLDS(A + aO1[0], (char*)As0 + lA1[0]);
  GLDS(A + aO1[1], (char*)As0 + lA1[1]);
  GLDS(B + bO1[0], (char*)Bs0 + lB1[0]);
  GLDS(B + bO1[1], (char*)Bs0 + lB1[1]);
  GLDS(B + bO2[0], (char*)Bs0 + lB2[0]);
  GLDS(B + bO2[1], (char*)Bs0 + lB2[1]);
  GLDS(A + aO2[0], (char*)As0 + lA2[0]);
  GLDS(A + aO2[1], (char*)As0 + lA2[1]);
  WAITVM4();    // A-lo, B-lo landed
  bar_raw();

  const ushort* cA = As0; const ushort* cB = Bs0;
  ushort* nA = As1; ushort* nB = Bs1;

  #pragma unroll 1
  for (int kt=0; kt<KT; ++kt){
    const u32 kk = (u32)(kt+1)*BK;   // tail garbage stays inside d_ws

    // ---- P0: read rAlo+rBlo(cur); stage A-lo(next); MFMA Q00; vm4 (retire B-hi cur)
    #pragma unroll
    for (int mi=0;mi<4;mi++)
      #pragma unroll
      for (int ks=0;ks<2;ks++)
        rAlo[mi][ks] = *(const bf16x8*)&cA[aRow[mi] + (o0 ^ (u32)(ks<<5))];
    #pragma unroll
    for (int ni=0;ni<2;ni++)
      #pragma unroll
      for (int ks=0;ks<2;ks++)
        rBlo[ni][ks] = *(const bf16x8*)&cB[bRow[ni] + (o0 ^ (u32)(ks<<5))];
    GLDS(A + aO1[0] + kk, (char*)nA + lA1[0]);
    GLDS(A + aO1[1] + kk, (char*)nA + lA1[1]);
    bar_raw(); WAITLGKM0(); SB0();
    __builtin_amdgcn_s_setprio(1);
    #pragma unroll
    for (int mi=0;mi<4;mi++)
      #pragma unroll
      for (int ni=0;ni<2;ni++)
        #pragma unroll
        for (int ks=0;ks<2;ks++)
          acc[mi][ni] = __builtin_amdgcn_mfma_f32_16x16x32_bf16(rAlo[mi][ks], rBlo[ni][ks], acc[mi][ni], 0, 0, 0);
    __builtin_amdgcn_s_setprio(0);
    WAITVM4();
    bar_raw();

    // ---- P1: read rBhi(cur); stage B-lo(next); MFMA Q01; vm4 (retire A-hi cur)
    #pragma unroll
    for (int ni=0;ni<2;ni++)
      #pragma unroll
      for (int ks=0;ks<2;ks++)
        rBhi[ni][ks] = *(const bf16x8*)&cB[bRow[ni+2] + (o0 ^ (u32)(ks<<5))];
    GLDS(B + bO1[0] + kk, (char*)nB + lB1[0]);
    GLDS(B + bO1[1] + kk, (char*)nB + lB1[1]);
    bar_raw(); WAITLGKM0(); SB0();
    __builtin_amdgcn_s_setprio(1);
    #pragma unroll
    for (int mi=0;mi<4;mi++)
      #pragma unroll
      for (int ni=0;ni<2;ni++)
        #pragma unroll
        for (int ks=0;ks<2;ks++)
          acc[mi][ni+2] = __builtin_amdgcn_mfma_f32_16x16x32_bf16(rAlo[mi][ks], rBhi[ni][ks], acc[mi][ni+2], 0, 0, 0);
    __builtin_amdgcn_s_setprio(0);
    WAITVM4();
    bar_raw();

    // ---- P2: read rAhi(cur); stage B-hi(next); MFMA Q10 (no vm wait)
    #pragma unroll
    for (int mi=0;mi<4;mi++)
      #pragma unroll
      for (int ks=0;ks<2;ks++)
        rAhi[mi][ks] = *(const bf16x8*)&cA[aRow[mi+4] + (o0 ^ (u32)(ks<<5))];
    GLDS(B + bO2[0] + kk, (char*)nB + lB2[0]);
    GLDS(B + bO2[1] + kk, (char*)nB + lB2[1]);
    bar_raw(); WAITLGKM0(); SB0();
    __builtin_amdgcn_s_setprio(1);
    #pragma unroll
    for (int mi=0;mi<4;mi++)
      #pragma unroll
      for (int ni=0;ni<2;ni++)
        #pragma unroll
        for (int ks=0;ks<2;ks++)
          acc[mi+4][ni] = __builtin_amdgcn_mfma_f32_16x16x32_bf16(rAhi[mi][ks], rBlo[ni][ks], acc[mi+4][ni], 0, 0, 0);
    __builtin_amdgcn_s_setprio(0);
    bar_raw();

    // ---- P3: stage A-hi(next); MFMA Q11; vm4 (retire A-lo,B-lo next)
    GLDS(A + aO2[0] + kk, (char*)nA + lA2[0]);
    GLDS(A + aO2[1] + kk, (char*)nA + lA2[1]);
    bar_raw();
    __builtin_amdgcn_s_setprio(1);
    #pragma unroll
    for (int mi=0;mi<4;mi++)
      #pragma unroll
      for (int ni=0;ni<2;ni++)
        #pragma unroll
        for (int ks=0;ks<2;ks++)
          acc[mi+4][ni+2] = __builtin_amdgcn_mfma_f32_16x16x32_bf16(rAhi[mi][ks], rBhi[ni][ks], acc[mi+4][ni+2], 0, 0, 0);
    __builtin_amdgcn_s_setprio(0);
    WAITVM4();
    bar_raw();

    ushort* t1 = (ushort*)cA; cA = nA; nA = t1;
    ushort* t2 = (ushort*)cB; cB = nB; nB = t2;
  }
  WAITVM0();   // drain tail garbage loads

  // epilogue: d2 = x2 + y2 - 2*dot ; min over this block's 256 columns, then atomicMin
  float xv[8][4];
  #pragma unroll
  for (int mi=0;mi<8;mi++)
    #pragma unroll
    for (int r=0;r<4;r++)
      xv[mi][r] = x2[min(m0 + wr*128 + mi*16 + cgrp*4 + r, NP-1)];

  u64 best[8][4];
  #pragma unroll
  for (int mi=0;mi<8;mi++)
    #pragma unroll
    for (int r=0;r<4;r++) best[mi][r] = ~0ull;

  #pragma unroll
  for (int ni=0;ni<4;ni++){
    const int n = n0 + wc*64 + ni*16 + ccol;
    const float yy = y2[n];
    #pragma unroll
    for (int mi=0;mi<8;mi++)
      #pragma unroll
      for (int r=0;r<4;r++){
        float d2 = fmaxf(xv[mi][r] + yy - 2.f*acc[mi][ni][r], 0.f);
        u64 pk = (((u64)__float_as_uint(d2))<<32) | (u32)n;
        if (pk < best[mi][r]) best[mi][r] = pk;
      }
  }

  #pragma unroll
  for (int mi=0;mi<8;mi++)
    #pragma unroll
    for (int r=0;r<4;r++){
      u64 pk = best[mi][r];
      #pragma unroll
      for (int md=1; md<16; md<<=1){
        u64 o = __shfl_xor(pk, md);
        if (o < pk) pk = o;
      }
      const int row = m0 + wr*128 + mi*16 + cgrp*4 + r;
      if (ccol==0 && row < NP) atomicMin(&packed[row], pk);
    }
}

__global__ void k_unpack(const u64* __restrict__ packed, float* __restrict__ patch_d, int* __restrict__ loc){
  int t = blockIdx.x*256 + threadIdx.x;
  if (t < NP){
    u64 v = packed[t];
    patch_d[t] = sqrtf(__uint_as_float((u32)(v>>32)));
    loc[t] = (int)(v & 0xffffffffu);
  }
}

// ---------------- per-batch argmax of patch scores ----------------
__global__ void k_argmax(const float* __restrict__ patch_d, const int* __restrict__ loc,
                         int* __restrict__ sel_mp, float* __restrict__ sel_score, int* __restrict__ sel_nn){
  int b = blockIdx.x;
  int tid = threadIdx.x;
  __shared__ u64 red[4];
  u64 best = 0;
  for (int p = tid; p < HO2*HO2; p += 256){
    float v = patch_d[b*HO2*HO2 + p];
    u64 pk = (((u64)__float_as_uint(v))<<32) | (u32)(HO2*HO2 - p);
    if (pk > best) best = pk;
  }
  int lane = tid & 63, w = tid >> 6;
  #pragma unroll
  for (int d=32; d; d>>=1){ u64 o = __shfl_down(best, d); if (o > best) best = o; }
  if (lane==0) red[w] = best;
  __syncthreads();
  if (tid==0){
    u64 bb = red[0];
    for (int q=1;q<4;q++) if (red[q] > bb) bb = red[q];
    int p = HO2*HO2 - (int)(bb & 0xffffffffu);
    sel_mp[b] = p;
    sel_score[b] = __uint_as_float((u32)(bb>>32));
    sel_nn[b] = loc[b*HO2*HO2 + p];
  }
}

// ---------------- d2(nn_sample[b], bank[m]) for all b,m (bf16 bank) ----------------
__device__ __forceinline__ void bf8dec(uint4 v, float* f){
  u32 a[4] = {v.x, v.y, v.z, v.w};
  #pragma unroll
  for (int q=0;q<4;q++){
    f[2*q]   = __uint_as_float(a[q]<<16);
    f[2*q+1] = __uint_as_float(a[q]&0xFFFF0000u);
  }
}

__global__ __launch_bounds__(256) void k_dbank(const ushort* __restrict__ bankB, const float* __restrict__ y2,
    const int* __restrict__ sel_nn, float* __restrict__ d_bank){
  int wave = threadIdx.x >> 6, lane = threadIdx.x & 63;
  int m = blockIdx.x*4 + wave;
  if (m >= NM) return;
  int nn[NB];
  #pragma unroll
  for (int b=0;b<NB;b++) nn[b] = sel_nn[b];
  const uint4* pm = (const uint4*)(bankB + (size_t)m*CC);
  float acc[NB];
  #pragma unroll
  for (int b=0;b<NB;b++) acc[b] = 0.f;
  #pragma unroll
  for (int it=0; it<3; ++it){
    uint4 v = pm[it*64 + lane];
    float vf[8]; bf8dec(v, vf);
    #pragma unroll
    for (int b=0;b<NB;b++){
      uint4 u = ((const uint4*)(bankB + (size_t)nn[b]*CC))[it*64 + lane];
      float uf[8]; bf8dec(u, uf);
      #pragma unroll
      for (int q=0;q<8;q++) acc[b] += vf[q]*uf[q];
    }
  }
  #pragma unroll
  for (int b=0;b<NB;b++){
    float s = warp_sum(acc[b]);
    if (lane==0) d_bank[(size_t)b*NM + m] = fmaxf(y2[nn[b]] + y2[m] - 2.f*s, 0.f);
  }
}

// ---------------- single-pass top-9 + anomaly score ----------------
__global__ __launch_bounds__(512) void k_score(const float* __restrict__ d_bank, const float* __restrict__ bank,
    const ushort* __restrict__ embB, const float* __restrict__ x2, const float* __restrict__ y2,
    const int* __restrict__ sel_mp, const float* __restrict__ sel_score, float* __restrict__ out_score){
  int b = blockIdx.x, tid = threadIdx.x;
  __shared__ u64 cand[512*NKNN];
  __shared__ int sel[NKNN];
  __shared__ u64 red[8];
  __shared__ u64 gbest_s;
  __shared__ float fred[8];
  __shared__ float sumexp_s;

  #pragma unroll
  for (int q=0;q<NKNN;q++) cand[tid*NKNN+q] = ~0ull;
  for (int m = tid; m < NM; m += 512){
    float v = d_bank[(size_t)b*NM + m];
    u64 pk = (((u64)__float_as_uint(v))<<32) | (u32)m;
    if (pk < cand[tid*NKNN + NKNN-1]){
      cand[tid*NKNN + NKNN-1] = pk;
      for (int q=NKNN-1; q>0 && cand[tid*NKNN+q] < cand[tid*NKNN+q-1]; --q){
        u64 t = cand[tid*NKNN+q]; cand[tid*NKNN+q] = cand[tid*NKNN+q-1]; cand[tid*NKNN+q-1] = t;
      }
    }
  }
  __syncthreads();
  int lane = tid & 63, w = tid >> 6;
  for (int k=0;k<NKNN;++k){
    u64 mybest = ~0ull;
    #pragma unroll
    for (int q=0;q<NKNN;q++){ u64 v = cand[tid*NKNN+q]; if (v < mybest) mybest = v; }
    u64 rb = mybest;
    #pragma unroll
    for (int d=32; d; d>>=1){ u64 o = __shfl_down(rb, d); if (o < rb) rb = o; }
    if (lane==0) red[w] = rb;
    __syncthreads();
    if (tid==0){
      u64 bb = red[0];
      for (int q=1;q<8;q++) if (red[q] < bb) bb = red[q];
      gbest_s = bb;
      sel[k] = (int)(bb & 0xffffffffu);
    }
    __syncthreads();
    u64 gb = gbest_s;
    #pragma unroll
    for (int q=0;q<NKNN;q++) if (cand[tid*NKNN+q] == gb) cand[tid*NKNN+q] = ~0ull;
    __syncthreads();
  }

  int mp = sel_mp[b];
  const ushort* fv = embB + (size_t)(b*HO2*HO2 + mp)*CC;
  float fx2 = x2[b*HO2*HO2 + mp];
  if (tid==0) sumexp_s = 0.f;
  __syncthreads();
  for (int k=0;k<NKNN;++k){
    const float* sv = bank + (size_t)sel[k]*CC;
    float part = 0.f;
    for (int i = tid; i < CC; i += 512) part += bf2f(fv[i])*sv[i];
    part = warp_sum(part);
    if (lane==0) fred[w] = part;
    __syncthreads();
    if (tid==0){
      float dot = 0.f;
      for (int q=0;q<8;q++) dot += fred[q];
      float d2 = fmaxf(fx2 + y2[sel[k]] - 2.f*dot, 0.f);
      sumexp_s += expf(sqrtf(d2));
    }
    __syncthreads();
  }
  if (tid==0){
    float s = sel_score[b];
    out_score[b] = (1.f - expf(s)/sumexp_s) * s;
  }
}

// ---------------- combined (blur ∘ bilinear) operator: T = G·R, 224x27 ----------------
__global__ void k_maketab(float* __restrict__ T, GW gw){
  int idx = blockIdx.x*256 + threadIdx.x;
  if (idx >= OH*HO2) return;
  int x = idx / HO2, j = idx - x*HO2;
  float s = 0.f;
  #pragma unroll
  for (int k=0;k<33;++k){
    int yy = x + k - 16;
    yy = (yy < 0) ? -yy : yy;
    yy = (yy > OH-1) ? (2*(OH-1) - yy) : yy;
    float fy = (yy + 0.5f) * (27.f/224.f) - 0.5f;
    int y0 = (int)floorf(fy); float wy = fy - (float)y0;
    int j0 = min(max(y0,0), HO2-1), j1 = min(max(y0+1,0), HO2-1);
    float c = ((j==j0)?(1.f-wy):0.f) + ((j==j1)?wy:0.f);
    s += gw.w[k]*c;
  }
  T[idx] = s;
}

// out_b = T · p_b · T^T  (one block per image)
__global__ __launch_bounds__(256) void k_amap_fused(const float* __restrict__ patch_d,
    const float* __restrict__ T, float* __restrict__ out){
  __shared__ float Ts[OH*HO2];    // [y][i], 24.2KB
  __shared__ float ps[HO2*HO2];
  __shared__ float tmp[HO2*OH];   // [i][x]
  int b = blockIdx.x, t = threadIdx.x;
  for (int idx=t; idx<OH*HO2; idx+=256) Ts[idx] = T[idx];
  for (int idx=t; idx<HO2*HO2; idx+=256) ps[idx] = patch_d[b*HO2*HO2+idx];
  __syncthreads();
  for (int idx=t; idx<HO2*OH; idx+=256){
    int i = idx/OH, x = idx - i*OH;
    float s = 0.f;
    #pragma unroll
    for (int j=0;j<HO2;j++) s += ps[i*HO2+j]*Ts[x*HO2+j];
    tmp[i*OH+x] = s;
  }
  __syncthreads();
  for (int idx=t; idx<OH*OH; idx+=256){
    int y = idx/OH, x = idx - y*OH;
    float s = 0.f;
    #pragma unroll
    for (int i=0;i<HO2;i++) s += Ts[y*HO2+i]*tmp[i*OH+x];
    out[(size_t)b*OH*OH + idx] = s;
  }
}

extern "C" void kernel_launch(void* const* d_in, const int* in_sizes, int n_in,
                              void* d_out, int out_size, void* d_ws, size_t ws_size,
                              hipStream_t stream){
  const float* f2   = (const float*)d_in[0];
  const float* f3   = (const float*)d_in[1];
  const float* bank = (const float*)d_in[2];
  float* out = (float*)d_out;

  char* ws = (char*)d_ws;
  size_t off = 0;
  auto alloc = [&](size_t bytes)->char*{ char* p = ws + off; off += (bytes + 255) & ~(size_t)255; return p; };
  ushort* embB    = (ushort*)alloc((size_t)NP*CC*2);
  ushort* bankB   = (ushort*)alloc((size_t)NM*CC*2);
  float* f3p      = (float*)alloc((size_t)NB*HO3*HO3*C3*4);
  float* y2       = (float*)alloc((size_t)NM*4);
  float* x2       = (float*)alloc((size_t)NP*4);
  u64*   packed   = (u64*)  alloc((size_t)NP*8);
  float* patch_d  = (float*)alloc((size_t)NP*4);
  int*   loc      = (int*)  alloc((size_t)NP*4);
  float* d_bank   = (float*)alloc((size_t)NB*NM*4);
  int*   sel_mp   = (int*)  alloc(NB*4);
  float* sel_scr  = (float*)alloc(NB*4);
  int*   sel_nn   = (int*)  alloc(NB*4);
  float* Tmat     = (float*)alloc((size_t)OH*HO2*4);

  GW gw;
  { float s=0.f; for(int i=0;i<33;i++){ float xx=(float)i-16.f; gw.w[i]=expf(-0.5f*(xx/4.f)*(xx/4.f)); s+=gw.w[i]; }
    for(int i=0;i<33;i++) gw.w[i]/=s; }

  k_avgpool2<<<NB*32,256,0,stream>>>(f2, embB);
  k_avgpool3<<<NB*16,256,0,stream>>>(f3, f3p);
  k_upsample3<<<(NB*HO2*HO2*C3+255)/256,256,0,stream>>>(f3p, embB);
  k_bank_prep<<<(NM+3)/4,256,0,stream>>>(bank, bankB, y2);
  k_rowsumsq_bf<<<(NP+3)/4,256,0,stream>>>(embB, x2, NP, packed);
  k_maketab<<<(OH*HO2+255)/256,256,0,stream>>>(Tmat, gw);
  k_distmin_mfma<<<NWG,512,0,stream>>>(embB, bankB, x2, y2, packed);
  k_unpack<<<(NP+255)/256,256,0,stream>>>(packed, patch_d, loc);
  k_argmax<<<NB,256,0,stream>>>(patch_d, loc, sel_mp, sel_scr, sel_nn);
  k_dbank<<<(NM+3)/4,256,0,stream>>>(bankB, y2, sel_nn, d_bank);
  k_score<<<NB,512,0,stream>>>(d_bank, bank, embB, x2, y2, sel_mp, sel_scr, out + AMAP_N);
  k_amap_fused<<<NB,256,0,stream>>>(patch_d, Tmat, out);
}